// Round 4
// baseline (464.312 us; speedup 1.0000x reference)
//
#include <hip/hip_runtime.h>
#include <hip/hip_cooperative_groups.h>
#include <math.h>

namespace cg = cooperative_groups;

#define CC 128
#define NN 4096   // 16*16*16
#define BB 2
#define NGROUPS 32
#define CPG 4
#define GSIZE (CPG*NN)          // 16384 elements per (b, group)
#define KSPLIT 8

typedef __attribute__((ext_vector_type(8))) __bf16 bf16x8;
typedef __attribute__((ext_vector_type(4))) float floatx4;

__device__ __forceinline__ unsigned short f2bf(float f) {
  union { float f; unsigned u; } v; v.f = f;
  unsigned r = v.u + 0x7fff + ((v.u >> 16) & 1);   // RNE
  return (unsigned short)(r >> 16);
}
__device__ __forceinline__ float bf2f(unsigned short u) {
  return __uint_as_float(((unsigned)u) << 16);
}

// Tiled layouts (per batch, NN*CC elements):
//  Q/K: elem(n,ch) at (n>>4)*2048 + (ch>>5)*512 + (n&15)*32 + (ch&31)
//  V:   elem(ch,m) at (m>>5)*4096 + (ch>>4)*512 + (ch&15)*32 + (m&31)
// LDS XOR-swizzle (T2, rule #21): pre-swizzle the GLOBAL source per lane
// (slot q -> q ^ ((row>>1)&3) within each 16-row x 32-short chunk) and apply
// the same XOR on the ds_read side -> 2 lanes/bank. (r3: measured neutral vs
// unswizzled — attn is not LDS-throughput-bound — kept because it's free.)

__device__ __forceinline__ void stage_tile(const unsigned short* __restrict__ gtile,
                                           unsigned short* ltile, int w, int lane) {
  int swl = ((lane >> 2) << 5) | ((((lane & 3) ^ ((lane >> 3) & 3))) << 3);
  #pragma unroll
  for (int j = 0; j < 4; j++) {
    int off = (w*4 + j) * 512;   // shorts
    __builtin_amdgcn_global_load_lds(
        (const __attribute__((address_space(1))) unsigned int*)(gtile + off + swl),
        (__attribute__((address_space(3))) unsigned int*)(ltile + off),
        16, 0, 0);
  }
}

// ---- shared-memory overlay for the fused kernel's 4 phases ----
struct S1 { float sred[4]; float ssred[4]; };
struct S2 { unsigned short hs[16][130]; unsigned short vs[16][136];
            float gm[NGROUPS]; float gr[NGROUPS]; float aa[CC]; float ab[CC]; };
struct S3 { unsigned short Kbuf[8192]; unsigned short Vbuf[8192];
            unsigned short Pl[4][32][88]; };              // 54 KB (largest)
struct S4 { unsigned short hs[16][130]; float ps[16][132]; float linv[16]; };
union SharedU { S1 s1; S2 s2; S3 s3; S4 s4; };

// ================= fused cooperative kernel: 512 blocks x 256 =================
// Phase map (flat bid 0..511):
//  P1: bid<256 GN partial sums; 256..319 weight f32->bf16; rest idle
//  P2: qkv   b=bid>>8, bx=bid&255
//  P3: attn  b=bid>>8, kh=(bid>>5)&7, bx=bid&31
//  P4: comb  b=bid>>8, bx=bid&255
// grid.sync() between phases replaces 3 kernel launches.
__global__ __launch_bounds__(256, 2) void fused_kernel(
    const float* __restrict__ x, const float* __restrict__ gamma, const float* __restrict__ beta,
    const float* __restrict__ wq, const float* __restrict__ bq,
    const float* __restrict__ wk, const float* __restrict__ bk,
    const float* __restrict__ wv, const float* __restrict__ bv,
    const float* __restrict__ wp, const float* __restrict__ bp,
    float2* __restrict__ stats,
    unsigned short* __restrict__ wqb, unsigned short* __restrict__ wkb,
    unsigned short* __restrict__ wvb, unsigned short* __restrict__ wpb,
    unsigned short* __restrict__ qb, unsigned short* __restrict__ kb,
    unsigned short* __restrict__ vb,
    unsigned short* __restrict__ Opart, float* __restrict__ lpart,
    float* __restrict__ out) {
  cg::grid_group grid = cg::this_grid();
  __shared__ SharedU su;
  const int bid = blockIdx.x;
  const int t   = threadIdx.x;

  // ---------------- phase 1: GN partial sums + weight conversion ----------------
  if (bid < 256) {
    const float4* base = (const float4*)(x + (size_t)bid * 4096);
    float4 v = base[t];
    float s  = v.x + v.y + v.z + v.w;
    float ss = v.x*v.x + v.y*v.y + v.z*v.z + v.w*v.w;
    #pragma unroll
    for (int off = 1; off < 64; off <<= 1) {
      s  += __shfl_xor(s, off);
      ss += __shfl_xor(ss, off);
    }
    if ((t & 63) == 0) { su.s1.sred[t >> 6] = s; su.s1.ssred[t >> 6] = ss; }
    __syncthreads();
    if (t == 0)
      stats[bid] = make_float2(su.s1.sred[0]+su.s1.sred[1]+su.s1.sred[2]+su.s1.sred[3],
                               su.s1.ssred[0]+su.s1.ssred[1]+su.s1.ssred[2]+su.s1.ssred[3]);
  } else if (bid < 320) {
    const float sc = 0.08838834764831845f;   // 128^-0.5, folded into wq
    int i = (bid - 256) * 256 + t;           // float4 index; 4096 per weight
    int id = i >> 12, local = i & 4095;
    const float* src = id==0 ? wq : id==1 ? wk : id==2 ? wv : wp;
    unsigned short* dst = id==0 ? wqb : id==1 ? wkb : id==2 ? wvb : wpb;
    float s = (id == 0) ? sc : 1.0f;
    float4 v = ((const float4*)src)[local];
    unsigned p0 = (unsigned)f2bf(v.x*s) | ((unsigned)f2bf(v.y*s) << 16);
    unsigned p1 = (unsigned)f2bf(v.z*s) | ((unsigned)f2bf(v.w*s) << 16);
    ((uint2*)dst)[local] = make_uint2(p0, p1);
  }
  __threadfence();
  grid.sync();

  // ---------------- phase 2: fused q/k/v ----------------
  {
    int b = bid >> 8, bx = bid & 255, n0 = bx * 16;
    if (t < NGROUPS) {
      float su_=0.f, ssq=0.f;
      #pragma unroll
      for (int j = 0; j < 4; j++) {
        float2 p = stats[(b*NGROUPS + t)*4 + j];
        su_ += p.x; ssq += p.y;
      }
      float mean = su_ * (1.0f/GSIZE);
      float var  = ssq * (1.0f/GSIZE) - mean*mean;
      su.s2.gm[t] = mean;
      su.s2.gr[t] = rsqrtf(var + 1e-5f);
    }
    __syncthreads();
    if (t < CC) {
      int g = t >> 2;
      float a = su.s2.gr[g] * gamma[t];
      su.s2.aa[t] = a;
      su.s2.ab[t] = beta[t] - su.s2.gm[g] * a;
    }
    __syncthreads();
    #pragma unroll
    for (int j = 0; j < 2; j++) {
      int idx = j*256 + t;
      int c = idx >> 2, n4 = idx & 3;
      float4 xv = *(const float4*)(x + ((size_t)b*CC + c)*NN + n0 + n4*4);
      float a = su.s2.aa[c], bc = su.s2.ab[c];
      su.s2.hs[n4*4+0][c] = f2bf(a*xv.x + bc);
      su.s2.hs[n4*4+1][c] = f2bf(a*xv.y + bc);
      su.s2.hs[n4*4+2][c] = f2bf(a*xv.z + bc);
      su.s2.hs[n4*4+3][c] = f2bf(a*xv.w + bc);
    }
    __syncthreads();
    int w = t >> 6, lane = t & 63, quad = lane >> 4, c = lane & 15;
    int o0 = w * 32;
    bf16x8 af[4];
    #pragma unroll
    for (int ks = 0; ks < 4; ks++)
      af[ks] = *(const bf16x8*)&su.s2.hs[c][ks*32 + quad*8];
    floatx4 aq[2], ak[2], av[2];
    #pragma unroll
    for (int ct = 0; ct < 2; ct++) {
      aq[ct] = (floatx4){0.f,0.f,0.f,0.f};
      ak[ct] = (floatx4){0.f,0.f,0.f,0.f};
      av[ct] = (floatx4){0.f,0.f,0.f,0.f};
    }
    #pragma unroll
    for (int ks = 0; ks < 4; ks++) {
      #pragma unroll
      for (int ct = 0; ct < 2; ct++) {
        size_t woff = (size_t)(o0 + ct*16 + c)*CC + ks*32 + quad*8;
        bf16x8 bq8 = *(const bf16x8*)(wqb + woff);
        bf16x8 bk8 = *(const bf16x8*)(wkb + woff);
        bf16x8 bv8 = *(const bf16x8*)(wvb + woff);
        aq[ct] = __builtin_amdgcn_mfma_f32_16x16x32_bf16(af[ks], bq8, aq[ct], 0, 0, 0);
        ak[ct] = __builtin_amdgcn_mfma_f32_16x16x32_bf16(af[ks], bk8, ak[ct], 0, 0, 0);
        av[ct] = __builtin_amdgcn_mfma_f32_16x16x32_bf16(af[ks], bv8, av[ct], 0, 0, 0);
      }
    }
    {
      const float sc = 0.08838834764831845f;
      size_t base = (size_t)b*NN*CC + (size_t)bx*2048 + w*512;
      #pragma unroll
      for (int ct = 0; ct < 2; ct++) {
        float bqi = bq[o0 + ct*16 + c] * sc;
        float bki = bk[o0 + ct*16 + c];
        #pragma unroll
        for (int r = 0; r < 4; r++) {
          int idx = (quad*4 + r)*32 + ct*16 + c;
          qb[base + idx] = f2bf(aq[ct][r] + bqi);
          kb[base + idx] = f2bf(ak[ct][r] + bki);
        }
      }
    }
    #pragma unroll
    for (int ct = 0; ct < 2; ct++) {
      float bvi = bv[o0 + ct*16 + c];
      #pragma unroll
      for (int r = 0; r < 4; r++)
        su.s2.vs[quad*4 + r][o0 + ct*16 + c] = f2bf(av[ct][r] + bvi);
    }
    __syncthreads();
    {
      int ch = t >> 1, part = t & 1;      // 8 m per thread
      int mbase = (n0 & 16) + part*8;
      unsigned pk[4];
      #pragma unroll
      for (int j = 0; j < 4; j++) {
        unsigned lo = su.s2.vs[part*8 + j*2    ][ch];
        unsigned hi = su.s2.vs[part*8 + j*2 + 1][ch];
        pk[j] = lo | (hi << 16);
      }
      *(uint4*)(vb + (size_t)b*NN*CC + ((size_t)(n0 >> 5))*4096 + (ch >> 4)*512
                + (ch & 15)*32 + mbase) = make_uint4(pk[0], pk[1], pk[2], pk[3]);
    }
  }
  __threadfence();
  grid.sync();

  // ---------------- phase 3: MFMA flash attention (KSPLIT partials) ----------------
  {
    int b  = bid >> 8;
    int kh = (bid >> 5) & 7;
    int bx = bid & 31;
    int w = t >> 6, lane = t & 63, quad = lane >> 4, c = lane & 15;
    int fragoff = c*32 + quad*8;                               // global (Q) frags
    int kvoff   = (c << 5) | (((quad ^ ((c >> 1) & 3))) << 3); // swizzled LDS frags

    bf16x8 qa[2][4];
    const unsigned short* qbase = qb + (size_t)b*NN*CC + ((size_t)(bx*8 + w*2))*2048;
    #pragma unroll
    for (int rt = 0; rt < 2; rt++)
      #pragma unroll
      for (int ks = 0; ks < 4; ks++)
        qa[rt][ks] = *(const bf16x8*)(qbase + rt*2048 + ks*512 + fragoff);

    floatx4 O[2][8];
    #pragma unroll
    for (int rt = 0; rt < 2; rt++)
      #pragma unroll
      for (int ct = 0; ct < 8; ct++) O[rt][ct] = (floatx4){0.f,0.f,0.f,0.f};
    float lsum[2] = {0.f, 0.f};

    const unsigned short* kt0 = kb + (size_t)b*NN*CC + (size_t)kh*(NN/KSPLIT)*CC;
    const unsigned short* vt0 = vb + (size_t)b*NN*CC + (size_t)kh*(NN/KSPLIT)*CC;

    const int ITERS = NN/KSPLIT/64;   // 8

    stage_tile(kt0, su.s3.Kbuf, w, lane);
    stage_tile(vt0, su.s3.Vbuf, w, lane);
    __syncthreads();

    for (int it = 0; it < ITERS; it++) {
      floatx4 ST[2][4];
      #pragma unroll
      for (int rt = 0; rt < 2; rt++)
        #pragma unroll
        for (int ct = 0; ct < 4; ct++) ST[rt][ct] = (floatx4){0.f,0.f,0.f,0.f};
      #pragma unroll
      for (int ks = 0; ks < 4; ks++) {
        #pragma unroll
        for (int ct = 0; ct < 4; ct++) {
          bf16x8 kf = *(const bf16x8*)&su.s3.Kbuf[ct*2048 + ks*512 + kvoff];
          ST[0][ct] = __builtin_amdgcn_mfma_f32_16x16x32_bf16(kf, qa[0][ks], ST[0][ct], 0, 0, 0);
          ST[1][ct] = __builtin_amdgcn_mfma_f32_16x16x32_bf16(kf, qa[1][ks], ST[1][ct], 0, 0, 0);
        }
      }
      #pragma unroll
      for (int rt = 0; rt < 2; rt++) {
        #pragma unroll
        for (int ct = 0; ct < 4; ct++) {
          float e0 = __expf(ST[rt][ct][0]);
          float e1 = __expf(ST[rt][ct][1]);
          float e2 = __expf(ST[rt][ct][2]);
          float e3 = __expf(ST[rt][ct][3]);
          lsum[rt] += (e0 + e1) + (e2 + e3);
          unsigned p01 = (__float_as_uint(e1) & 0xffff0000u) | (__float_as_uint(e0) >> 16);
          unsigned p23 = (__float_as_uint(e3) & 0xffff0000u) | (__float_as_uint(e2) >> 16);
          *(uint2*)&su.s3.Pl[w][rt*16 + c][ct*16 + quad*4] = make_uint2(p01, p23);
        }
      }
      __syncthreads();
      if (it+1 < ITERS) stage_tile(kt0 + (size_t)(it+1)*8192, su.s3.Kbuf, w, lane);
      #pragma unroll
      for (int ks2 = 0; ks2 < 2; ks2++) {
        bf16x8 pa0 = *(const bf16x8*)(&su.s3.Pl[w][c     ][ks2*32 + quad*8]);
        bf16x8 pa1 = *(const bf16x8*)(&su.s3.Pl[w][16 + c][ks2*32 + quad*8]);
        #pragma unroll
        for (int ct = 0; ct < 8; ct++) {
          bf16x8 vf = *(const bf16x8*)&su.s3.Vbuf[ks2*4096 + ct*512 + kvoff];
          O[0][ct] = __builtin_amdgcn_mfma_f32_16x16x32_bf16(pa0, vf, O[0][ct], 0, 0, 0);
          O[1][ct] = __builtin_amdgcn_mfma_f32_16x16x32_bf16(pa1, vf, O[1][ct], 0, 0, 0);
        }
      }
      __syncthreads();
      if (it+1 < ITERS) stage_tile(vt0 + (size_t)(it+1)*8192, su.s3.Vbuf, w, lane);
    }

    size_t nbase = (size_t)(kh*BB + b)*NN + bx*128 + w*32;
    #pragma unroll
    for (int rt = 0; rt < 2; rt++) {
      float vsum = lsum[rt];
      vsum += __shfl_xor(vsum, 16);
      vsum += __shfl_xor(vsum, 32);
      if (lane < 16) lpart[nbase + rt*16 + lane] = vsum;
    }
    bool odd = (c & 1);
    int colpair = (c & ~1);
    #pragma unroll
    for (int rt = 0; rt < 2; rt++) {
      #pragma unroll
      for (int ct = 0; ct < 8; ct++) {
        unsigned u0 = f2bf(O[rt][ct][0]);
        unsigned u1 = f2bf(O[rt][ct][1]);
        unsigned u2 = f2bf(O[rt][ct][2]);
        unsigned u3 = f2bf(O[rt][ct][3]);
        unsigned s01 = odd ? u0 : u1;
        unsigned g01 = __shfl_xor((int)s01, 1);
        unsigned p0 = odd ? (g01 | (u1 << 16)) : (u0 | (g01 << 16));
        unsigned s23 = odd ? u2 : u3;
        unsigned g23 = __shfl_xor((int)s23, 1);
        unsigned p1 = odd ? (g23 | (u3 << 16)) : (u2 | (g23 << 16));
        int rowA = rt*16 + quad*4 + (odd ? 1 : 0);
        int rowB = rt*16 + quad*4 + (odd ? 3 : 2);
        *(unsigned*)(Opart + (nbase + rowA)*CC + ct*16 + colpair) = p0;
        *(unsigned*)(Opart + (nbase + rowB)*CC + ct*16 + colpair) = p1;
      }
    }
  }
  __threadfence();
  grid.sync();

  // ---------------- phase 4: combine + proj + residual ----------------
  {
    int b = bid >> 8, n0 = (bid & 255) * 16;
    if (t < 16) {
      float l = 0.f;
      #pragma unroll
      for (int kh = 0; kh < KSPLIT; kh++)
        l += lpart[((size_t)(kh*BB + b))*NN + n0 + t];
      su.s4.linv[t] = 1.f / l;
    }
    __syncthreads();
    {
      int n = t >> 4, ch0 = (t & 15) * 8;
      float acc[8];
      #pragma unroll
      for (int j = 0; j < 8; j++) acc[j] = 0.f;
      #pragma unroll
      for (int kh = 0; kh < KSPLIT; kh++) {
        uint4 a = *(const uint4*)(Opart + ((size_t)(kh*BB + b)*NN + n0 + n)*CC + ch0);
        unsigned uu[4] = {a.x, a.y, a.z, a.w};
        #pragma unroll
        for (int j = 0; j < 4; j++) {
          acc[j*2    ] += bf2f((unsigned short)(uu[j] & 0xffff));
          acc[j*2 + 1] += bf2f((unsigned short)(uu[j] >> 16));
        }
      }
      float li = su.s4.linv[n];
      #pragma unroll
      for (int j = 0; j < 8; j++) su.s4.hs[n][ch0 + j] = f2bf(acc[j] * li);
    }
    __syncthreads();
    int w = t >> 6, lane = t & 63, quad = lane >> 4, c = lane & 15;
    int o0 = w * 32;
    floatx4 acc[2];
    #pragma unroll
    for (int ct = 0; ct < 2; ct++) acc[ct] = (floatx4){0.f,0.f,0.f,0.f};
    #pragma unroll
    for (int ks = 0; ks < 4; ks++) {
      bf16x8 af = *(const bf16x8*)&su.s4.hs[c][ks*32 + quad*8];
      #pragma unroll
      for (int ct = 0; ct < 2; ct++) {
        bf16x8 bfr = *(const bf16x8*)(wpb + (size_t)(o0 + ct*16 + c)*CC + ks*32 + quad*8);
        acc[ct] = __builtin_amdgcn_mfma_f32_16x16x32_bf16(af, bfr, acc[ct], 0, 0, 0);
      }
    }
    #pragma unroll
    for (int ct = 0; ct < 2; ct++)
      #pragma unroll
      for (int r = 0; r < 4; r++)
        su.s4.ps[quad*4 + r][o0 + ct*16 + c] = acc[ct][r];
    __syncthreads();
    int o = t >> 1, nh = (t & 1) * 8;
    float bi = bp[o];
    const float* xr = x + ((size_t)b*CC + o)*NN + n0 + nh;
    float* orow = out + ((size_t)b*CC + o)*NN + n0 + nh;
    #pragma unroll
    for (int j4 = 0; j4 < 2; j4++) {
      float4 xv = ((const float4*)xr)[j4];
      float4 ov;
      ov.x = xv.x + su.s4.ps[nh + j4*4 + 0][o] + bi;
      ov.y = xv.y + su.s4.ps[nh + j4*4 + 1][o] + bi;
      ov.z = xv.z + su.s4.ps[nh + j4*4 + 2][o] + bi;
      ov.w = xv.w + su.s4.ps[nh + j4*4 + 3][o] + bi;
      ((float4*)orow)[j4] = ov;
    }
  }
}

// ================= fallback: original 4-kernel pipeline (unchanged) =================
__global__ void gn_stats_kernel(const float* __restrict__ x, float2* __restrict__ stats,
                                const float* __restrict__ wq, const float* __restrict__ wk,
                                const float* __restrict__ wv, const float* __restrict__ wp,
                                unsigned short* __restrict__ wqb, unsigned short* __restrict__ wkb,
                                unsigned short* __restrict__ wvb, unsigned short* __restrict__ wpb) {
  int t = threadIdx.x;
  if (blockIdx.x < 256) {
    int bid = blockIdx.x;
    const float4* base = (const float4*)(x + (size_t)bid * 4096);
    float4 v = base[t];
    float s  = v.x + v.y + v.z + v.w;
    float ss = v.x*v.x + v.y*v.y + v.z*v.z + v.w*v.w;
    #pragma unroll
    for (int off = 1; off < 64; off <<= 1) {
      s  += __shfl_xor(s, off);
      ss += __shfl_xor(ss, off);
    }
    __shared__ float sred[4], ssred[4];
    if ((t & 63) == 0) { sred[t >> 6] = s; ssred[t >> 6] = ss; }
    __syncthreads();
    if (t == 0)
      stats[bid] = make_float2(sred[0]+sred[1]+sred[2]+sred[3],
                               ssred[0]+ssred[1]+ssred[2]+ssred[3]);
  } else {
    const float sc = 0.08838834764831845f;
    int i = (blockIdx.x - 256) * 256 + t;
    int id = i >> 12, local = i & 4095;
    const float* src = id==0 ? wq : id==1 ? wk : id==2 ? wv : wp;
    unsigned short* dst = id==0 ? wqb : id==1 ? wkb : id==2 ? wvb : wpb;
    float s = (id == 0) ? sc : 1.0f;
    float4 v = ((const float4*)src)[local];
    unsigned p0 = (unsigned)f2bf(v.x*s) | ((unsigned)f2bf(v.y*s) << 16);
    unsigned p1 = (unsigned)f2bf(v.z*s) | ((unsigned)f2bf(v.w*s) << 16);
    ((uint2*)dst)[local] = make_uint2(p0, p1);
  }
}

__global__ __launch_bounds__(256, 2) void qkv_kernel(
    const float* __restrict__ x, const float2* __restrict__ stats,
    const float* __restrict__ gamma, const float* __restrict__ beta,
    const unsigned short* __restrict__ wqb, const unsigned short* __restrict__ wkb,
    const unsigned short* __restrict__ wvb,
    const float* __restrict__ bq, const float* __restrict__ bk, const float* __restrict__ bv,
    unsigned short* __restrict__ q, unsigned short* __restrict__ k, unsigned short* __restrict__ v) {
  int b = blockIdx.y, n0 = blockIdx.x * 16;
  __shared__ unsigned short hs[16][130];
  __shared__ unsigned short vs[16][136];
  __shared__ float gm[NGROUPS], gr[NGROUPS], aa[CC], ab[CC];
  int t = threadIdx.x;
  if (t < NGROUPS) {
    float su = 0.f, ssq = 0.f;
    #pragma unroll
    for (int j = 0; j < 4; j++) {
      float2 p = stats[(b*NGROUPS + t)*4 + j];
      su += p.x; ssq += p.y;
    }
    float mean = su * (1.0f/GSIZE);
    float var  = ssq * (1.0f/GSIZE) - mean*mean;
    gm[t] = mean;
    gr[t] = rsqrtf(var + 1e-5f);
  }
  __syncthreads();
  if (t < CC) {
    int g = t >> 2;
    float a = gr[g] * gamma[t];
    aa[t] = a;
    ab[t] = beta[t] - gm[g] * a;
  }
  __syncthreads();
  #pragma unroll
  for (int j = 0; j < 2; j++) {
    int idx = j*256 + t;
    int c = idx >> 2, n4 = idx & 3;
    float4 xv = *(const float4*)(x + ((size_t)b*CC + c)*NN + n0 + n4*4);
    float a = aa[c], bc = ab[c];
    hs[n4*4+0][c] = f2bf(a*xv.x + bc);
    hs[n4*4+1][c] = f2bf(a*xv.y + bc);
    hs[n4*4+2][c] = f2bf(a*xv.z + bc);
    hs[n4*4+3][c] = f2bf(a*xv.w + bc);
  }
  __syncthreads();
  int w = t >> 6, lane = t & 63, quad = lane >> 4, c = lane & 15;
  int o0 = w * 32;
  bf16x8 af[4];
  #pragma unroll
  for (int ks = 0; ks < 4; ks++)
    af[ks] = *(const bf16x8*)&hs[c][ks*32 + quad*8];
  floatx4 aq[2], ak[2], av[2];
  #pragma unroll
  for (int ct = 0; ct < 2; ct++) {
    aq[ct] = (floatx4){0.f,0.f,0.f,0.f};
    ak[ct] = (floatx4){0.f,0.f,0.f,0.f};
    av[ct] = (floatx4){0.f,0.f,0.f,0.f};
  }
  #pragma unroll
  for (int ks = 0; ks < 4; ks++) {
    #pragma unroll
    for (int ct = 0; ct < 2; ct++) {
      size_t woff = (size_t)(o0 + ct*16 + c)*CC + ks*32 + quad*8;
      bf16x8 bq8 = *(const bf16x8*)(wqb + woff);
      bf16x8 bk8 = *(const bf16x8*)(wkb + woff);
      bf16x8 bv8 = *(const bf16x8*)(wvb + woff);
      aq[ct] = __builtin_amdgcn_mfma_f32_16x16x32_bf16(af[ks], bq8, aq[ct], 0, 0, 0);
      ak[ct] = __builtin_amdgcn_mfma_f32_16x16x32_bf16(af[ks], bk8, ak[ct], 0, 0, 0);
      av[ct] = __builtin_amdgcn_mfma_f32_16x16x32_bf16(af[ks], bv8, av[ct], 0, 0, 0);
    }
  }
  {
    const float sc = 0.08838834764831845f;
    size_t base = (size_t)b*NN*CC + (size_t)blockIdx.x*2048 + w*512;
    #pragma unroll
    for (int ct = 0; ct < 2; ct++) {
      float bqi = bq[o0 + ct*16 + c] * sc;
      float bki = bk[o0 + ct*16 + c];
      #pragma unroll
      for (int r = 0; r < 4; r++) {
        int idx = (quad*4 + r)*32 + ct*16 + c;
        q[base + idx] = f2bf(aq[ct][r] + bqi);
        k[base + idx] = f2bf(ak[ct][r] + bki);
      }
    }
  }
  #pragma unroll
  for (int ct = 0; ct < 2; ct++) {
    float bvi = bv[o0 + ct*16 + c];
    #pragma unroll
    for (int r = 0; r < 4; r++)
      vs[quad*4 + r][o0 + ct*16 + c] = f2bf(av[ct][r] + bvi);
  }
  __syncthreads();
  {
    int ch = t >> 1, part = t & 1;
    int mbase = (n0 & 16) + part*8;
    unsigned pk[4];
    #pragma unroll
    for (int j = 0; j < 4; j++) {
      unsigned lo = vs[part*8 + j*2    ][ch];
      unsigned hi = vs[part*8 + j*2 + 1][ch];
      pk[j] = lo | (hi << 16);
    }
    *(uint4*)(v + (size_t)b*NN*CC + ((size_t)(n0 >> 5))*4096 + (ch >> 4)*512
              + (ch & 15)*32 + mbase) = make_uint4(pk[0], pk[1], pk[2], pk[3]);
  }
}

__global__ __launch_bounds__(256, 2) void attn_kernel(
    const unsigned short* __restrict__ qm, const unsigned short* __restrict__ km,
    const unsigned short* __restrict__ vm,
    unsigned short* __restrict__ Opart, float* __restrict__ lpart) {
  int b    = blockIdx.z;
  int kh   = blockIdx.y;
  int t    = threadIdx.x;
  int w    = t >> 6, lane = t & 63, quad = lane >> 4, c = lane & 15;

  __shared__ unsigned short Kbuf[8192];
  __shared__ unsigned short Vbuf[8192];
  __shared__ unsigned short Pl[4][32][88];

  int fragoff = c*32 + quad*8;
  int kvoff   = (c << 5) | (((quad ^ ((c >> 1) & 3))) << 3);

  bf16x8 qa[2][4];
  const unsigned short* qbase = qm + (size_t)b*NN*CC + ((size_t)(blockIdx.x*8 + w*2))*2048;
  #pragma unroll
  for (int rt = 0; rt < 2; rt++)
    #pragma unroll
    for (int ks = 0; ks < 4; ks++)
      qa[rt][ks] = *(const bf16x8*)(qbase + rt*2048 + ks*512 + fragoff);

  floatx4 O[2][8];
  #pragma unroll
  for (int rt = 0; rt < 2; rt++)
    #pragma unroll
    for (int ct = 0; ct < 8; ct++) O[rt][ct] = (floatx4){0.f,0.f,0.f,0.f};
  float lsum[2] = {0.f, 0.f};

  const unsigned short* kt0 = km + (size_t)b*NN*CC + (size_t)kh*(NN/KSPLIT)*CC;
  const unsigned short* vt0 = vm + (size_t)b*NN*CC + (size_t)kh*(NN/KSPLIT)*CC;

  const int ITERS = NN/KSPLIT/64;

  stage_tile(kt0, Kbuf, w, lane);
  stage_tile(vt0, Vbuf, w, lane);
  __syncthreads();

  for (int it = 0; it < ITERS; it++) {
    floatx4 ST[2][4];
    #pragma unroll
    for (int rt = 0; rt < 2; rt++)
      #pragma unroll
      for (int ct = 0; ct < 4; ct++) ST[rt][ct] = (floatx4){0.f,0.f,0.f,0.f};
    #pragma unroll
    for (int ks = 0; ks < 4; ks++) {
      #pragma unroll
      for (int ct = 0; ct < 4; ct++) {
        bf16x8 kf = *(const bf16x8*)&Kbuf[ct*2048 + ks*512 + kvoff];
        ST[0][ct] = __builtin_amdgcn_mfma_f32_16x16x32_bf16(kf, qa[0][ks], ST[0][ct], 0, 0, 0);
        ST[1][ct] = __builtin_amdgcn_mfma_f32_16x16x32_bf16(kf, qa[1][ks], ST[1][ct], 0, 0, 0);
      }
    }
    #pragma unroll
    for (int rt = 0; rt < 2; rt++) {
      #pragma unroll
      for (int ct = 0; ct < 4; ct++) {
        float e0 = __expf(ST[rt][ct][0]);
        float e1 = __expf(ST[rt][ct][1]);
        float e2 = __expf(ST[rt][ct][2]);
        float e3 = __expf(ST[rt][ct][3]);
        lsum[rt] += (e0 + e1) + (e2 + e3);
        unsigned p01 = (__float_as_uint(e1) & 0xffff0000u) | (__float_as_uint(e0) >> 16);
        unsigned p23 = (__float_as_uint(e3) & 0xffff0000u) | (__float_as_uint(e2) >> 16);
        *(uint2*)&Pl[w][rt*16 + c][ct*16 + quad*4] = make_uint2(p01, p23);
      }
    }
    __syncthreads();
    if (it+1 < ITERS) stage_tile(kt0 + (size_t)(it+1)*8192, Kbuf, w, lane);
    #pragma unroll
    for (int ks2 = 0; ks2 < 2; ks2++) {
      bf16x8 pa0 = *(const bf16x8*)(&Pl[w][c     ][ks2*32 + quad*8]);
      bf16x8 pa1 = *(const bf16x8*)(&Pl[w][16 + c][ks2*32 + quad*8]);
      #pragma unroll
      for (int ct = 0; ct < 8; ct++) {
        bf16x8 vf = *(const bf16x8*)&Vbuf[ks2*4096 + ct*512 + kvoff];
        O[0][ct] = __builtin_amdgcn_mfma_f32_16x16x32_bf16(pa0, vf, O[0][ct], 0, 0, 0);
        O[1][ct] = __builtin_amdgcn_mfma_f32_16x16x32_bf16(pa1, vf, O[1][ct], 0, 0, 0);
      }
    }
    __syncthreads();
    if (it+1 < ITERS) stage_tile(vt0 + (size_t)(it+1)*8192, Vbuf, w, lane);
  }

  size_t nbase = (size_t)(kh*BB + b)*NN + blockIdx.x*128 + w*32;
  #pragma unroll
  for (int rt = 0; rt < 2; rt++) {
    float vsum = lsum[rt];
    vsum += __shfl_xor(vsum, 16);
    vsum += __shfl_xor(vsum, 32);
    if (lane < 16) lpart[nbase + rt*16 + lane] = vsum;
  }
  bool odd = (c & 1);
  int colpair = (c & ~1);
  #pragma unroll
  for (int rt = 0; rt < 2; rt++) {
    #pragma unroll
    for (int ct = 0; ct < 8; ct++) {
      unsigned u0 = f2bf(O[rt][ct][0]);
      unsigned u1 = f2bf(O[rt][ct][1]);
      unsigned u2 = f2bf(O[rt][ct][2]);
      unsigned u3 = f2bf(O[rt][ct][3]);
      unsigned s01 = odd ? u0 : u1;
      unsigned g01 = __shfl_xor((int)s01, 1);
      unsigned p0 = odd ? (g01 | (u1 << 16)) : (u0 | (g01 << 16));
      unsigned s23 = odd ? u2 : u3;
      unsigned g23 = __shfl_xor((int)s23, 1);
      unsigned p1 = odd ? (g23 | (u3 << 16)) : (u2 | (g23 << 16));
      int rowA = rt*16 + quad*4 + (odd ? 1 : 0);
      int rowB = rt*16 + quad*4 + (odd ? 3 : 2);
      *(unsigned*)(Opart + (nbase + rowA)*CC + ct*16 + colpair) = p0;
      *(unsigned*)(Opart + (nbase + rowB)*CC + ct*16 + colpair) = p1;
    }
  }
}

__global__ __launch_bounds__(256, 2) void combine_kernel(
    const unsigned short* __restrict__ Opart, const float* __restrict__ lpart,
    const unsigned short* __restrict__ wpb, const float* __restrict__ bp,
    const float* __restrict__ x, float* __restrict__ out) {
  int b = blockIdx.y, n0 = blockIdx.x * 16;
  int t = threadIdx.x;
  __shared__ unsigned short hs[16][130];
  __shared__ float ps[16][132];
  __shared__ float linv[16];
  if (t < 16) {
    float l = 0.f;
    #pragma unroll
    for (int kh = 0; kh < KSPLIT; kh++)
      l += lpart[((size_t)(kh*BB + b))*NN + n0 + t];
    linv[t] = 1.f / l;
  }
  __syncthreads();
  {
    int n = t >> 4, ch0 = (t & 15) * 8;
    float acc[8];
    #pragma unroll
    for (int j = 0; j < 8; j++) acc[j] = 0.f;
    #pragma unroll
    for (int kh = 0; kh < KSPLIT; kh++) {
      uint4 a = *(const uint4*)(Opart + ((size_t)(kh*BB + b)*NN + n0 + n)*CC + ch0);
      unsigned uu[4] = {a.x, a.y, a.z, a.w};
      #pragma unroll
      for (int j = 0; j < 4; j++) {
        acc[j*2    ] += bf2f((unsigned short)(uu[j] & 0xffff));
        acc[j*2 + 1] += bf2f((unsigned short)(uu[j] >> 16));
      }
    }
    float li = linv[n];
    #pragma unroll
    for (int j = 0; j < 8; j++) hs[n][ch0 + j] = f2bf(acc[j] * li);
  }
  __syncthreads();
  int w = t >> 6, lane = t & 63, quad = lane >> 4, c = lane & 15;
  int o0 = w * 32;
  floatx4 acc[2];
  #pragma unroll
  for (int ct = 0; ct < 2; ct++) acc[ct] = (floatx4){0.f,0.f,0.f,0.f};
  #pragma unroll
  for (int ks = 0; ks < 4; ks++) {
    bf16x8 af = *(const bf16x8*)&hs[c][ks*32 + quad*8];
    #pragma unroll
    for (int ct = 0; ct < 2; ct++) {
      bf16x8 bfr = *(const bf16x8*)(wpb + (size_t)(o0 + ct*16 + c)*CC + ks*32 + quad*8);
      acc[ct] = __builtin_amdgcn_mfma_f32_16x16x32_bf16(af, bfr, acc[ct], 0, 0, 0);
    }
  }
  #pragma unroll
  for (int ct = 0; ct < 2; ct++)
    #pragma unroll
    for (int r = 0; r < 4; r++)
      ps[quad*4 + r][o0 + ct*16 + c] = acc[ct][r];
  __syncthreads();
  int o = t >> 1, nh = (t & 1) * 8;
  float bi = bp[o];
  const float* xr = x + ((size_t)b*CC + o)*NN + n0 + nh;
  float* orow = out + ((size_t)b*CC + o)*NN + n0 + nh;
  #pragma unroll
  for (int j4 = 0; j4 < 2; j4++) {
    float4 xv = ((const float4*)xr)[j4];
    float4 ov;
    ov.x = xv.x + ps[nh + j4*4 + 0][o] + bi;
    ov.y = xv.y + ps[nh + j4*4 + 1][o] + bi;
    ov.z = xv.z + ps[nh + j4*4 + 2][o] + bi;
    ov.w = xv.w + ps[nh + j4*4 + 3][o] + bi;
    ((float4*)orow)[j4] = ov;
  }
}

extern "C" void kernel_launch(void* const* d_in, const int* in_sizes, int n_in,
                              void* d_out, int out_size, void* d_ws, size_t ws_size,
                              hipStream_t stream) {
  const float* x    = (const float*)d_in[0];
  const float* gn_w = (const float*)d_in[1];
  const float* gn_b = (const float*)d_in[2];
  const float* wq   = (const float*)d_in[3];
  const float* bq   = (const float*)d_in[4];
  const float* wk   = (const float*)d_in[5];
  const float* bk   = (const float*)d_in[6];
  const float* wv   = (const float*)d_in[7];
  const float* bv   = (const float*)d_in[8];
  const float* wp   = (const float*)d_in[9];
  const float* bp   = (const float*)d_in[10];
  float* out = (float*)d_out;

  char* ws = (char*)d_ws;
  float2*         stats = (float2*)(ws);                       // 2048 B
  unsigned short* wqb   = (unsigned short*)(ws + 8192);        // 32 KiB each
  unsigned short* wkb   = (unsigned short*)(ws + 8192 + 32768);
  unsigned short* wvb   = (unsigned short*)(ws + 8192 + 65536);
  unsigned short* wpb   = (unsigned short*)(ws + 8192 + 98304);
  unsigned short* qb    = (unsigned short*)(ws + 262144);                  // 2 MiB
  unsigned short* kb    = (unsigned short*)(ws + 262144 + 2097152);        // 2 MiB
  unsigned short* vb    = (unsigned short*)(ws + 262144 + 2*2097152);      // 2 MiB
  unsigned short* Opart = (unsigned short*)(ws + 6553600);                 // 16 MiB
  float*          lpart = (float*)(ws + 6553600 + 16777216);               // 256 KiB

  void* kargs[] = {
    (void*)&x, (void*)&gn_w, (void*)&gn_b,
    (void*)&wq, (void*)&bq, (void*)&wk, (void*)&bk,
    (void*)&wv, (void*)&bv, (void*)&wp, (void*)&bp,
    (void*)&stats, (void*)&wqb, (void*)&wkb, (void*)&wvb, (void*)&wpb,
    (void*)&qb, (void*)&kb, (void*)&vb,
    (void*)&Opart, (void*)&lpart, (void*)&out
  };
  hipError_t err = hipLaunchCooperativeKernel((const void*)fused_kernel,
                                              dim3(512), dim3(256),
                                              kargs, 0, stream);
  if (err != hipSuccess) {
    // fallback: original 4-kernel pipeline
    gn_stats_kernel<<<dim3(320), 256, 0, stream>>>(x, stats, wq, wk, wv, wp,
                                                   wqb, wkb, wvb, wpb);
    qkv_kernel     <<<dim3(NN/16, BB), 256, 0, stream>>>(x, stats, gn_w, gn_b,
                                                         wqb, wkb, wvb, bq, bk, bv,
                                                         qb, kb, vb);
    attn_kernel    <<<dim3(NN/128, KSPLIT, BB), 256, 0, stream>>>(qb, kb, vb, Opart, lpart);
    combine_kernel <<<dim3(NN/16, BB), 256, 0, stream>>>(Opart, lpart, wpb, bp, x, out);
  }
}

// Round 6
// 201.886 us; speedup vs baseline: 2.2999x; 2.2999x over previous
//
#include <hip/hip_runtime.h>
#include <math.h>

#define CC 128
#define NN 4096   // 16*16*16
#define BB 2
#define NGROUPS 32
#define CPG 4
#define GSIZE (CPG*NN)          // 16384 elements per (b, group)
#define KSPLIT 8

// ---- DIAGNOSTIC REPEATS (r4): idempotent inner loops push each kernel past
// the 40 us fillBuffer rows so all three show in rocprof top-5 with their own
// counters. Per-iter cost = dur/REP. REVERT TO 1 after attribution. ----
#define REP_QKV  12
#define REP_ATTN 4
#define REP_COMB 10

typedef __attribute__((ext_vector_type(8))) __bf16 bf16x8;
typedef __attribute__((ext_vector_type(4))) float floatx4;

__device__ __forceinline__ unsigned short f2bf(float f) {
  union { float f; unsigned u; } v; v.f = f;
  unsigned r = v.u + 0x7fff + ((v.u >> 16) & 1);   // RNE
  return (unsigned short)(r >> 16);
}
__device__ __forceinline__ float bf2f(unsigned short u) {
  return __uint_as_float(((unsigned)u) << 16);
}

// Tiled layouts (per batch, NN*CC elements):
//  Q/K: elem(n,ch) at (n>>4)*2048 + (ch>>5)*512 + (n&15)*32 + (ch&31)
//  V:   elem(ch,m) at (m>>5)*4096 + (ch>>4)*512 + (ch&15)*32 + (m&31)
// LDS XOR-swizzle kept from r0 (measured neutral r3 — for ds_read_b128 the
// un-swizzled pattern was already bank-uniform; swizzle is free, retained).

__device__ __forceinline__ void stage_tile(const unsigned short* __restrict__ gtile,
                                           unsigned short* ltile, int w, int lane) {
  int swl = ((lane >> 2) << 5) | ((((lane & 3) ^ ((lane >> 3) & 3))) << 3);
  #pragma unroll
  for (int j = 0; j < 4; j++) {
    int off = (w*4 + j) * 512;   // shorts
    __builtin_amdgcn_global_load_lds(
        (const __attribute__((address_space(1))) unsigned int*)(gtile + off + swl),
        (__attribute__((address_space(3))) unsigned int*)(ltile + off),
        16, 0, 0);
  }
}

// ---- stage 1 (320 blocks): 0-255 GN partial sums; 256-319 weight f32->bf16 ----
__global__ void gn_stats_kernel(const float* __restrict__ x, float2* __restrict__ stats,
                                const float* __restrict__ wq, const float* __restrict__ wk,
                                const float* __restrict__ wv, const float* __restrict__ wp,
                                unsigned short* __restrict__ wqb, unsigned short* __restrict__ wkb,
                                unsigned short* __restrict__ wvb, unsigned short* __restrict__ wpb) {
  int t = threadIdx.x;
  if (blockIdx.x < 256) {
    int bid = blockIdx.x;
    const float4* base = (const float4*)(x + (size_t)bid * 4096);
    float4 v = base[t];
    float s  = v.x + v.y + v.z + v.w;
    float ss = v.x*v.x + v.y*v.y + v.z*v.z + v.w*v.w;
    #pragma unroll
    for (int off = 1; off < 64; off <<= 1) {
      s  += __shfl_xor(s, off);
      ss += __shfl_xor(ss, off);
    }
    __shared__ float sred[4], ssred[4];
    if ((t & 63) == 0) { sred[t >> 6] = s; ssred[t >> 6] = ss; }
    __syncthreads();
    if (t == 0)
      stats[bid] = make_float2(sred[0]+sred[1]+sred[2]+sred[3],
                               ssred[0]+ssred[1]+ssred[2]+ssred[3]);
  } else {
    const float sc = 0.08838834764831845f;   // 128^-0.5, folded into wq
    int i = (blockIdx.x - 256) * 256 + t;    // float4 index; 4096 per weight
    int id = i >> 12, local = i & 4095;
    const float* src = id==0 ? wq : id==1 ? wk : id==2 ? wv : wp;
    unsigned short* dst = id==0 ? wqb : id==1 ? wkb : id==2 ? wvb : wpb;
    float s = (id == 0) ? sc : 1.0f;
    float4 v = ((const float4*)src)[local];
    unsigned p0 = (unsigned)f2bf(v.x*s) | ((unsigned)f2bf(v.y*s) << 16);
    unsigned p1 = (unsigned)f2bf(v.z*s) | ((unsigned)f2bf(v.w*s) << 16);
    ((uint2*)dst)[local] = make_uint2(p0, p1);
  }
}

// ---- fused q/k/v ----
__global__ __launch_bounds__(256, 2) void qkv_kernel(
    const float* __restrict__ x, const float2* __restrict__ stats,
    const float* __restrict__ gamma, const float* __restrict__ beta,
    const unsigned short* __restrict__ wqb, const unsigned short* __restrict__ wkb,
    const unsigned short* __restrict__ wvb,
    const float* __restrict__ bq, const float* __restrict__ bk, const float* __restrict__ bv,
    unsigned short* __restrict__ q, unsigned short* __restrict__ k, unsigned short* __restrict__ v) {
  int b = blockIdx.y, n0 = blockIdx.x * 16;
  __shared__ unsigned short hs[16][130];   // normalized x tile, bf16 [n][c]
  __shared__ unsigned short vs[16][136];   // v transpose staging
  __shared__ float gm[NGROUPS], gr[NGROUPS], aa[CC], ab[CC];
  int t = threadIdx.x;
  #pragma unroll 1
  for (int rep = 0; rep < REP_QKV; ++rep) {
  __syncthreads();
  if (t < NGROUPS) {
    float su = 0.f, ssq = 0.f;
    #pragma unroll
    for (int j = 0; j < 4; j++) {
      float2 p = stats[(b*NGROUPS + t)*4 + j];
      su += p.x; ssq += p.y;
    }
    float mean = su * (1.0f/GSIZE);
    float var  = ssq * (1.0f/GSIZE) - mean*mean;
    gm[t] = mean;
    gr[t] = rsqrtf(var + 1e-5f);
  }
  __syncthreads();
  if (t < CC) {
    int g = t >> 2;
    float a = gr[g] * gamma[t];
    aa[t] = a;
    ab[t] = beta[t] - gm[g] * a;
  }
  __syncthreads();
  #pragma unroll
  for (int j = 0; j < 2; j++) {
    int idx = j*256 + t;
    int c = idx >> 2, n4 = idx & 3;
    float4 xv = *(const float4*)(x + ((size_t)b*CC + c)*NN + n0 + n4*4);
    float a = aa[c], bc = ab[c];
    hs[n4*4+0][c] = f2bf(a*xv.x + bc);
    hs[n4*4+1][c] = f2bf(a*xv.y + bc);
    hs[n4*4+2][c] = f2bf(a*xv.z + bc);
    hs[n4*4+3][c] = f2bf(a*xv.w + bc);
  }
  __syncthreads();
  int w = t >> 6, lane = t & 63, quad = lane >> 4, c = lane & 15;
  int o0 = w * 32;
  bf16x8 af[4];
  #pragma unroll
  for (int ks = 0; ks < 4; ks++)
    af[ks] = *(const bf16x8*)&hs[c][ks*32 + quad*8];
  floatx4 aq[2], ak[2], av[2];
  #pragma unroll
  for (int ct = 0; ct < 2; ct++) {
    aq[ct] = (floatx4){0.f,0.f,0.f,0.f};
    ak[ct] = (floatx4){0.f,0.f,0.f,0.f};
    av[ct] = (floatx4){0.f,0.f,0.f,0.f};
  }
  #pragma unroll
  for (int ks = 0; ks < 4; ks++) {
    #pragma unroll
    for (int ct = 0; ct < 2; ct++) {
      size_t woff = (size_t)(o0 + ct*16 + c)*CC + ks*32 + quad*8;
      bf16x8 bq8 = *(const bf16x8*)(wqb + woff);
      bf16x8 bk8 = *(const bf16x8*)(wkb + woff);
      bf16x8 bv8 = *(const bf16x8*)(wvb + woff);
      aq[ct] = __builtin_amdgcn_mfma_f32_16x16x32_bf16(af[ks], bq8, aq[ct], 0, 0, 0);
      ak[ct] = __builtin_amdgcn_mfma_f32_16x16x32_bf16(af[ks], bk8, ak[ct], 0, 0, 0);
      av[ct] = __builtin_amdgcn_mfma_f32_16x16x32_bf16(af[ks], bv8, av[ct], 0, 0, 0);
    }
  }
  {
    const float sc = 0.08838834764831845f;
    size_t base = (size_t)b*NN*CC + (size_t)blockIdx.x*2048 + w*512;
    #pragma unroll
    for (int ct = 0; ct < 2; ct++) {
      float bqi = bq[o0 + ct*16 + c] * sc;
      float bki = bk[o0 + ct*16 + c];
      #pragma unroll
      for (int r = 0; r < 4; r++) {
        int idx = (quad*4 + r)*32 + ct*16 + c;
        q[base + idx] = f2bf(aq[ct][r] + bqi);
        k[base + idx] = f2bf(ak[ct][r] + bki);
      }
    }
  }
  #pragma unroll
  for (int ct = 0; ct < 2; ct++) {
    float bvi = bv[o0 + ct*16 + c];
    #pragma unroll
    for (int r = 0; r < 4; r++)
      vs[quad*4 + r][o0 + ct*16 + c] = f2bf(av[ct][r] + bvi);
  }
  __syncthreads();
  {
    int ch = t >> 1, part = t & 1;      // 8 m per thread
    int mbase = (n0 & 16) + part*8;
    unsigned pk[4];
    #pragma unroll
    for (int j = 0; j < 4; j++) {
      unsigned lo = vs[part*8 + j*2    ][ch];
      unsigned hi = vs[part*8 + j*2 + 1][ch];
      pk[j] = lo | (hi << 16);
    }
    *(uint4*)(v + (size_t)b*NN*CC + ((size_t)(n0 >> 5))*4096 + (ch >> 4)*512
              + (ch & 15)*32 + mbase) = make_uint4(pk[0], pk[1], pk[2], pk[3]);
  }
  }  // rep
}

// ---- MFMA flash attention ----
__global__ __launch_bounds__(256, 2) void attn_kernel(
    const unsigned short* __restrict__ qm, const unsigned short* __restrict__ km,
    const unsigned short* __restrict__ vm,
    unsigned short* __restrict__ Opart, float* __restrict__ lpart) {
  int b    = blockIdx.z;
  int kh   = blockIdx.y;
  int t    = threadIdx.x;
  int w    = t >> 6, lane = t & 63, quad = lane >> 4, c = lane & 15;

  __shared__ unsigned short Kbuf[8192];
  __shared__ unsigned short Vbuf[8192];
  __shared__ unsigned short Pl[4][32][88];

  int fragoff = c*32 + quad*8;
  int kvoff   = (c << 5) | (((quad ^ ((c >> 1) & 3))) << 3);

  #pragma unroll 1
  for (int rep = 0; rep < REP_ATTN; ++rep) {
  bf16x8 qa[2][4];
  const unsigned short* qbase = qm + (size_t)b*NN*CC + ((size_t)(blockIdx.x*8 + w*2))*2048;
  #pragma unroll
  for (int rt = 0; rt < 2; rt++)
    #pragma unroll
    for (int ks = 0; ks < 4; ks++)
      qa[rt][ks] = *(const bf16x8*)(qbase + rt*2048 + ks*512 + fragoff);

  floatx4 O[2][8];
  #pragma unroll
  for (int rt = 0; rt < 2; rt++)
    #pragma unroll
    for (int ct = 0; ct < 8; ct++) O[rt][ct] = (floatx4){0.f,0.f,0.f,0.f};
  float lsum[2] = {0.f, 0.f};

  const unsigned short* kt0 = km + (size_t)b*NN*CC + (size_t)kh*(NN/KSPLIT)*CC;
  const unsigned short* vt0 = vm + (size_t)b*NN*CC + (size_t)kh*(NN/KSPLIT)*CC;

  const int ITERS = NN/KSPLIT/64;   // 8

  stage_tile(kt0, Kbuf, w, lane);
  stage_tile(vt0, Vbuf, w, lane);
  __syncthreads();

  for (int it = 0; it < ITERS; it++) {
    floatx4 ST[2][4];
    #pragma unroll
    for (int rt = 0; rt < 2; rt++)
      #pragma unroll
      for (int ct = 0; ct < 4; ct++) ST[rt][ct] = (floatx4){0.f,0.f,0.f,0.f};
    #pragma unroll
    for (int ks = 0; ks < 4; ks++) {
      #pragma unroll
      for (int ct = 0; ct < 4; ct++) {
        bf16x8 kf = *(const bf16x8*)&Kbuf[ct*2048 + ks*512 + kvoff];
        ST[0][ct] = __builtin_amdgcn_mfma_f32_16x16x32_bf16(kf, qa[0][ks], ST[0][ct], 0, 0, 0);
        ST[1][ct] = __builtin_amdgcn_mfma_f32_16x16x32_bf16(kf, qa[1][ks], ST[1][ct], 0, 0, 0);
      }
    }
    #pragma unroll
    for (int rt = 0; rt < 2; rt++) {
      #pragma unroll
      for (int ct = 0; ct < 4; ct++) {
        float e0 = __expf(ST[rt][ct][0]);
        float e1 = __expf(ST[rt][ct][1]);
        float e2 = __expf(ST[rt][ct][2]);
        float e3 = __expf(ST[rt][ct][3]);
        lsum[rt] += (e0 + e1) + (e2 + e3);
        unsigned p01 = (__float_as_uint(e1) & 0xffff0000u) | (__float_as_uint(e0) >> 16);
        unsigned p23 = (__float_as_uint(e3) & 0xffff0000u) | (__float_as_uint(e2) >> 16);
        *(uint2*)&Pl[w][rt*16 + c][ct*16 + quad*4] = make_uint2(p01, p23);
      }
    }
    __syncthreads();
    if (it+1 < ITERS) stage_tile(kt0 + (size_t)(it+1)*8192, Kbuf, w, lane);
    #pragma unroll
    for (int ks2 = 0; ks2 < 2; ks2++) {
      bf16x8 pa0 = *(const bf16x8*)(&Pl[w][c     ][ks2*32 + quad*8]);
      bf16x8 pa1 = *(const bf16x8*)(&Pl[w][16 + c][ks2*32 + quad*8]);
      #pragma unroll
      for (int ct = 0; ct < 8; ct++) {
        bf16x8 vf = *(const bf16x8*)&Vbuf[ks2*4096 + ct*512 + kvoff];
        O[0][ct] = __builtin_amdgcn_mfma_f32_16x16x32_bf16(pa0, vf, O[0][ct], 0, 0, 0);
        O[1][ct] = __builtin_amdgcn_mfma_f32_16x16x32_bf16(pa1, vf, O[1][ct], 0, 0, 0);
      }
    }
    __syncthreads();
    if (it+1 < ITERS) stage_tile(vt0 + (size_t)(it+1)*8192, Vbuf, w, lane);
  }

  size_t nbase = (size_t)(kh*BB + b)*NN + blockIdx.x*128 + w*32;
  #pragma unroll
  for (int rt = 0; rt < 2; rt++) {
    float vsum = lsum[rt];
    vsum += __shfl_xor(vsum, 16);
    vsum += __shfl_xor(vsum, 32);
    if (lane < 16) lpart[nbase + rt*16 + lane] = vsum;
  }
  bool odd = (c & 1);
  int colpair = (c & ~1);
  #pragma unroll
  for (int rt = 0; rt < 2; rt++) {
    #pragma unroll
    for (int ct = 0; ct < 8; ct++) {
      unsigned u0 = f2bf(O[rt][ct][0]);
      unsigned u1 = f2bf(O[rt][ct][1]);
      unsigned u2 = f2bf(O[rt][ct][2]);
      unsigned u3 = f2bf(O[rt][ct][3]);
      unsigned s01 = odd ? u0 : u1;
      unsigned g01 = __shfl_xor((int)s01, 1);
      unsigned p0 = odd ? (g01 | (u1 << 16)) : (u0 | (g01 << 16));
      unsigned s23 = odd ? u2 : u3;
      unsigned g23 = __shfl_xor((int)s23, 1);
      unsigned p1 = odd ? (g23 | (u3 << 16)) : (u2 | (g23 << 16));
      int rowA = rt*16 + quad*4 + (odd ? 1 : 0);
      int rowB = rt*16 + quad*4 + (odd ? 3 : 2);
      *(unsigned*)(Opart + (nbase + rowA)*CC + ct*16 + colpair) = p0;
      *(unsigned*)(Opart + (nbase + rowB)*CC + ct*16 + colpair) = p1;
    }
  }
  __syncthreads();   // LDS quiesced before next rep restages
  }  // rep
}

// ---- combine 8 partials + normalize + proj (MFMA) + bias + residual ----
__global__ __launch_bounds__(256, 2) void combine_kernel(
    const unsigned short* __restrict__ Opart, const float* __restrict__ lpart,
    const unsigned short* __restrict__ wpb, const float* __restrict__ bp,
    const float* __restrict__ x, float* __restrict__ out) {
  int b = blockIdx.y, n0 = blockIdx.x * 16;
  int t = threadIdx.x;
  __shared__ unsigned short hs[16][130];
  __shared__ float ps[16][132];
  __shared__ float linv[16];
  #pragma unroll 1
  for (int rep = 0; rep < REP_COMB; ++rep) {
  if (t < 16) {
    float l = 0.f;
    #pragma unroll
    for (int kh = 0; kh < KSPLIT; kh++)
      l += lpart[((size_t)(kh*BB + b))*NN + n0 + t];
    linv[t] = 1.f / l;
  }
  __syncthreads();
  {
    int n = t >> 4, ch0 = (t & 15) * 8;
    float acc[8];
    #pragma unroll
    for (int j = 0; j < 8; j++) acc[j] = 0.f;
    #pragma unroll
    for (int kh = 0; kh < KSPLIT; kh++) {
      uint4 a = *(const uint4*)(Opart + ((size_t)(kh*BB + b)*NN + n0 + n)*CC + ch0);
      unsigned uu[4] = {a.x, a.y, a.z, a.w};
      #pragma unroll
      for (int j = 0; j < 4; j++) {
        acc[j*2    ] += bf2f((unsigned short)(uu[j] & 0xffff));
        acc[j*2 + 1] += bf2f((unsigned short)(uu[j] >> 16));
      }
    }
    float li = linv[n];
    #pragma unroll
    for (int j = 0; j < 8; j++) hs[n][ch0 + j] = f2bf(acc[j] * li);
  }
  __syncthreads();
  int w = t >> 6, lane = t & 63, quad = lane >> 4, c = lane & 15;
  int o0 = w * 32;
  floatx4 acc[2];
  #pragma unroll
  for (int ct = 0; ct < 2; ct++) acc[ct] = (floatx4){0.f,0.f,0.f,0.f};
  #pragma unroll
  for (int ks = 0; ks < 4; ks++) {
    bf16x8 af = *(const bf16x8*)&hs[c][ks*32 + quad*8];
    #pragma unroll
    for (int ct = 0; ct < 2; ct++) {
      bf16x8 bfr = *(const bf16x8*)(wpb + (size_t)(o0 + ct*16 + c)*CC + ks*32 + quad*8);
      acc[ct] = __builtin_amdgcn_mfma_f32_16x16x32_bf16(af, bfr, acc[ct], 0, 0, 0);
    }
  }
  #pragma unroll
  for (int ct = 0; ct < 2; ct++)
    #pragma unroll
    for (int r = 0; r < 4; r++)
      ps[quad*4 + r][o0 + ct*16 + c] = acc[ct][r];
  __syncthreads();
  int o = t >> 1, nh = (t & 1) * 8;
  float bi = bp[o];
  const float* xr = x + ((size_t)b*CC + o)*NN + n0 + nh;
  float* orow = out + ((size_t)b*CC + o)*NN + n0 + nh;
  #pragma unroll
  for (int j4 = 0; j4 < 2; j4++) {
    float4 xv = ((const float4*)xr)[j4];
    float4 ov;
    ov.x = xv.x + ps[nh + j4*4 + 0][o] + bi;
    ov.y = xv.y + ps[nh + j4*4 + 1][o] + bi;
    ov.z = xv.z + ps[nh + j4*4 + 2][o] + bi;
    ov.w = xv.w + ps[nh + j4*4 + 3][o] + bi;
    ((float4*)orow)[j4] = ov;
  }
  __syncthreads();   // ps/linv quiesced before next rep rewrites
  }  // rep
}

extern "C" void kernel_launch(void* const* d_in, const int* in_sizes, int n_in,
                              void* d_out, int out_size, void* d_ws, size_t ws_size,
                              hipStream_t stream) {
  const float* x    = (const float*)d_in[0];
  const float* gn_w = (const float*)d_in[1];
  const float* gn_b = (const float*)d_in[2];
  const float* wq   = (const float*)d_in[3];
  const float* bq   = (const float*)d_in[4];
  const float* wk   = (const float*)d_in[5];
  const float* bk   = (const float*)d_in[6];
  const float* wv   = (const float*)d_in[7];
  const float* bv   = (const float*)d_in[8];
  const float* wp   = (const float*)d_in[9];
  const float* bp   = (const float*)d_in[10];
  float* out = (float*)d_out;

  char* ws = (char*)d_ws;
  float2*         stats = (float2*)(ws);                       // 2048 B
  unsigned short* wqb   = (unsigned short*)(ws + 8192);        // 32 KiB each
  unsigned short* wkb   = (unsigned short*)(ws + 8192 + 32768);
  unsigned short* wvb   = (unsigned short*)(ws + 8192 + 65536);
  unsigned short* wpb   = (unsigned short*)(ws + 8192 + 98304);
  unsigned short* qb    = (unsigned short*)(ws + 262144);                  // 2 MiB
  unsigned short* kb    = (unsigned short*)(ws + 262144 + 2097152);        // 2 MiB
  unsigned short* vb    = (unsigned short*)(ws + 262144 + 2*2097152);      // 2 MiB
  unsigned short* Opart = (unsigned short*)(ws + 6553600);                 // 16 MiB
  float*          lpart = (float*)(ws + 6553600 + 16777216);               // 256 KiB

  gn_stats_kernel<<<dim3(320), 256, 0, stream>>>(x, stats, wq, wk, wv, wp,
                                                 wqb, wkb, wvb, wpb);
  qkv_kernel     <<<dim3(NN/16, BB), 256, 0, stream>>>(x, stats, gn_w, gn_b,
                                                       wqb, wkb, wvb, bq, bk, bv,
                                                       qb, kb, vb);
  attn_kernel    <<<dim3(NN/128, KSPLIT, BB), 256, 0, stream>>>(qb, kb, vb, Opart, lpart);
  combine_kernel <<<dim3(NN/16, BB), 256, 0, stream>>>(Opart, lpart, wpb, bp, x, out);
}

// Round 7
// 125.987 us; speedup vs baseline: 3.6854x; 1.6024x over previous
//
#include <hip/hip_runtime.h>
#include <math.h>

#define CC 128
#define NN 4096   // 16*16*16
#define BB 2
#define NGROUPS 32
#define CPG 4
#define GSIZE (CPG*NN)          // 16384 elements per (b, group)
#define KSPLIT 8

typedef __attribute__((ext_vector_type(8))) __bf16 bf16x8;
typedef __attribute__((ext_vector_type(4))) float floatx4;

__device__ __forceinline__ unsigned short f2bf(float f) {
  union { float f; unsigned u; } v; v.f = f;
  unsigned r = v.u + 0x7fff + ((v.u >> 16) & 1);   // RNE
  return (unsigned short)(r >> 16);
}
__device__ __forceinline__ float bf2f(unsigned short u) {
  return __uint_as_float(((unsigned)u) << 16);
}

// Tiled layouts (per batch, NN*CC elements):
//  Q/K: elem(n,ch) at (n>>4)*2048 + (ch>>5)*512 + (n&15)*32 + (ch&31)
//  V:   elem(ch,m) at (m>>5)*4096 + (ch>>4)*512 + (ch&15)*32 + (m&31)
//
// r6 diagnostic: attn = 24.3 us of the ~31 us controllable budget (harness
// poison fills ~85 us are fixed). attn LDS pipe ~53% busy + 2-barrier/iter
// idle. This round: V from global->regs (L1-served, -44% LDS traffic),
// K double-buffered (1 barrier/iter), exp2-fold (log2e into q scale).
// Q-scale INCLUDES log2e: exp(S) == exp2(S') with S' = S*log2e.

// one wave stages 4 KB (4 chunks of 1 KB); K-path only now.
// XOR-swizzle (r0): source slot q -> q ^ ((row>>1)&3) per 16-row x 32-short
// chunk; read side applies same XOR (kvoff). Identity: LDS[kvoff] == global
// element at plain fragoff.
__device__ __forceinline__ void stage_tile(const unsigned short* __restrict__ gtile,
                                           unsigned short* ltile, int w, int lane) {
  int swl = ((lane >> 2) << 5) | ((((lane & 3) ^ ((lane >> 3) & 3))) << 3);
  #pragma unroll
  for (int j = 0; j < 4; j++) {
    int off = (w*4 + j) * 512;   // shorts
    __builtin_amdgcn_global_load_lds(
        (const __attribute__((address_space(1))) unsigned int*)(gtile + off + swl),
        (__attribute__((address_space(3))) unsigned int*)(ltile + off),
        16, 0, 0);
  }
}

// ---- stage 1 (320 blocks): 0-255 GN partial sums; 256-319 weight f32->bf16 ----
__global__ void gn_stats_kernel(const float* __restrict__ x, float2* __restrict__ stats,
                                const float* __restrict__ wq, const float* __restrict__ wk,
                                const float* __restrict__ wv, const float* __restrict__ wp,
                                unsigned short* __restrict__ wqb, unsigned short* __restrict__ wkb,
                                unsigned short* __restrict__ wvb, unsigned short* __restrict__ wpb) {
  int t = threadIdx.x;
  if (blockIdx.x < 256) {
    int bid = blockIdx.x;
    const float4* base = (const float4*)(x + (size_t)bid * 4096);
    float4 v = base[t];
    float s  = v.x + v.y + v.z + v.w;
    float ss = v.x*v.x + v.y*v.y + v.z*v.z + v.w*v.w;
    #pragma unroll
    for (int off = 1; off < 64; off <<= 1) {
      s  += __shfl_xor(s, off);
      ss += __shfl_xor(ss, off);
    }
    __shared__ float sred[4], ssred[4];
    if ((t & 63) == 0) { sred[t >> 6] = s; ssred[t >> 6] = ss; }
    __syncthreads();
    if (t == 0)
      stats[bid] = make_float2(sred[0]+sred[1]+sred[2]+sred[3],
                               ssred[0]+ssred[1]+ssred[2]+ssred[3]);
  } else {
    const float sc = 0.1275174389522736f;    // 128^-0.5 * log2(e), folded into wq
    int i = (blockIdx.x - 256) * 256 + t;    // float4 index; 4096 per weight
    int id = i >> 12, local = i & 4095;
    const float* src = id==0 ? wq : id==1 ? wk : id==2 ? wv : wp;
    unsigned short* dst = id==0 ? wqb : id==1 ? wkb : id==2 ? wvb : wpb;
    float s = (id == 0) ? sc : 1.0f;
    float4 v = ((const float4*)src)[local];
    unsigned p0 = (unsigned)f2bf(v.x*s) | ((unsigned)f2bf(v.y*s) << 16);
    unsigned p1 = (unsigned)f2bf(v.z*s) | ((unsigned)f2bf(v.w*s) << 16);
    ((uint2*)dst)[local] = make_uint2(p0, p1);
  }
}

// ---- fused q/k/v: one 16-row tile per block computes all three convs (A-frags
// loaded once, reused 3x). grid (NN/16, BB) = 512 blocks, 2/CU. ----
__global__ __launch_bounds__(256, 2) void qkv_kernel(
    const float* __restrict__ x, const float2* __restrict__ stats,
    const float* __restrict__ gamma, const float* __restrict__ beta,
    const unsigned short* __restrict__ wqb, const unsigned short* __restrict__ wkb,
    const unsigned short* __restrict__ wvb,
    const float* __restrict__ bq, const float* __restrict__ bk, const float* __restrict__ bv,
    unsigned short* __restrict__ q, unsigned short* __restrict__ k, unsigned short* __restrict__ v) {
  int b = blockIdx.y, n0 = blockIdx.x * 16;
  __shared__ unsigned short hs[16][130];   // normalized x tile, bf16 [n][c]
  __shared__ unsigned short vs[16][136];   // v transpose staging
  __shared__ float gm[NGROUPS], gr[NGROUPS], aa[CC], ab[CC];
  int t = threadIdx.x;
  if (t < NGROUPS) {
    float su = 0.f, ssq = 0.f;
    #pragma unroll
    for (int j = 0; j < 4; j++) {
      float2 p = stats[(b*NGROUPS + t)*4 + j];
      su += p.x; ssq += p.y;
    }
    float mean = su * (1.0f/GSIZE);
    float var  = ssq * (1.0f/GSIZE) - mean*mean;
    gm[t] = mean;
    gr[t] = rsqrtf(var + 1e-5f);
  }
  __syncthreads();
  if (t < CC) {
    int g = t >> 2;
    float a = gr[g] * gamma[t];
    aa[t] = a;
    ab[t] = beta[t] - gm[g] * a;
  }
  __syncthreads();
  // x tile: 16 rows x 128 ch = 512 float4 over 256 threads
  #pragma unroll
  for (int j = 0; j < 2; j++) {
    int idx = j*256 + t;
    int c = idx >> 2, n4 = idx & 3;
    float4 xv = *(const float4*)(x + ((size_t)b*CC + c)*NN + n0 + n4*4);
    float a = aa[c], bc = ab[c];
    hs[n4*4+0][c] = f2bf(a*xv.x + bc);
    hs[n4*4+1][c] = f2bf(a*xv.y + bc);
    hs[n4*4+2][c] = f2bf(a*xv.z + bc);
    hs[n4*4+3][c] = f2bf(a*xv.w + bc);
  }
  __syncthreads();
  int w = t >> 6, lane = t & 63, quad = lane >> 4, c = lane & 15;
  int o0 = w * 32;
  bf16x8 af[4];
  #pragma unroll
  for (int ks = 0; ks < 4; ks++)
    af[ks] = *(const bf16x8*)&hs[c][ks*32 + quad*8];
  floatx4 aq[2], ak[2], av[2];
  #pragma unroll
  for (int ct = 0; ct < 2; ct++) {
    aq[ct] = (floatx4){0.f,0.f,0.f,0.f};
    ak[ct] = (floatx4){0.f,0.f,0.f,0.f};
    av[ct] = (floatx4){0.f,0.f,0.f,0.f};
  }
  #pragma unroll
  for (int ks = 0; ks < 4; ks++) {
    #pragma unroll
    for (int ct = 0; ct < 2; ct++) {
      size_t woff = (size_t)(o0 + ct*16 + c)*CC + ks*32 + quad*8;
      bf16x8 bq8 = *(const bf16x8*)(wqb + woff);
      bf16x8 bk8 = *(const bf16x8*)(wkb + woff);
      bf16x8 bv8 = *(const bf16x8*)(wvb + woff);
      aq[ct] = __builtin_amdgcn_mfma_f32_16x16x32_bf16(af[ks], bq8, aq[ct], 0, 0, 0);
      ak[ct] = __builtin_amdgcn_mfma_f32_16x16x32_bf16(af[ks], bk8, ak[ct], 0, 0, 0);
      av[ct] = __builtin_amdgcn_mfma_f32_16x16x32_bf16(af[ks], bv8, av[ct], 0, 0, 0);
    }
  }
  // q,k tiled stores: this block covers exactly n-tile blockIdx.x
  {
    const float sc = 0.1275174389522736f;   // matches wq fold (incl. log2e)
    size_t base = (size_t)b*NN*CC + (size_t)blockIdx.x*2048 + w*512;
    #pragma unroll
    for (int ct = 0; ct < 2; ct++) {
      float bqi = bq[o0 + ct*16 + c] * sc;
      float bki = bk[o0 + ct*16 + c];
      #pragma unroll
      for (int r = 0; r < 4; r++) {
        int idx = (quad*4 + r)*32 + ct*16 + c;
        q[base + idx] = f2bf(aq[ct][r] + bqi);
        k[base + idx] = f2bf(ak[ct][r] + bki);
      }
    }
  }
  // v transpose via LDS then tiled V store
  #pragma unroll
  for (int ct = 0; ct < 2; ct++) {
    float bvi = bv[o0 + ct*16 + c];
    #pragma unroll
    for (int r = 0; r < 4; r++)
      vs[quad*4 + r][o0 + ct*16 + c] = f2bf(av[ct][r] + bvi);
  }
  __syncthreads();
  {
    // elem(ch,m): (m>>5)*4096 + (ch>>4)*512 + (ch&15)*32 + (m&31); our m = n0..n0+15
    int ch = t >> 1, part = t & 1;      // 8 m per thread
    int mbase = (n0 & 16) + part*8;
    unsigned pk[4];
    #pragma unroll
    for (int j = 0; j < 4; j++) {
      unsigned lo = vs[part*8 + j*2    ][ch];
      unsigned hi = vs[part*8 + j*2 + 1][ch];
      pk[j] = lo | (hi << 16);
    }
    *(uint4*)(v + (size_t)b*NN*CC + ((size_t)(n0 >> 5))*4096 + (ch >> 4)*512
              + (ch & 15)*32 + mbase) = make_uint4(pk[0], pk[1], pk[2], pk[3]);
  }
}

// ---- MFMA flash attention: 128 q-rows/block (4 waves x 32).
// r7 structure: K double-buffered in LDS (1 barrier/iter, staging overlaps the
// whole iter); V loaded global->regs per iter (L1-served across the 4 waves,
// bypasses LDS: -44% LDS traffic vs r6's 53%-busy LDS pipe); softmax uses
// exp2 (log2e pre-folded into q). Pl is wave-private (no barrier needed
// between its write and read; DS ops are in-order within a wave).
// LDS 55.3 KB, grid (32, KSPLIT=8, B) = 512 blocks, 2/CU. ----
__global__ __launch_bounds__(256, 2) void attn_kernel(
    const unsigned short* __restrict__ qm,  // tiled QK layout, q-scale (incl log2e) folded
    const unsigned short* __restrict__ km,  // tiled QK layout
    const unsigned short* __restrict__ vm,  // tiled V layout
    unsigned short* __restrict__ Opart,     // [KSPLIT][B][N][C] bf16, unnormalized
    float* __restrict__ lpart) {            // [KSPLIT][B][N] f32
  int b    = blockIdx.z;
  int kh   = blockIdx.y;
  int t    = threadIdx.x;
  int w    = t >> 6, lane = t & 63, quad = lane >> 4, c = lane & 15;

  __shared__ unsigned short Kbuf[2][8192];   // 2 x 16 KB double buffer
  __shared__ unsigned short Pl[4][32][88];   // wave-private P, [q_row][k]

  int fragoff = c*32 + quad*8;                               // natural frag offset
  int kvoff   = (c << 5) | (((quad ^ ((c >> 1) & 3))) << 3); // swizzled LDS frag (K)

  bf16x8 qa[2][4];
  const unsigned short* qbase = qm + (size_t)b*NN*CC + ((size_t)(blockIdx.x*8 + w*2))*2048;
  #pragma unroll
  for (int rt = 0; rt < 2; rt++)
    #pragma unroll
    for (int ks = 0; ks < 4; ks++)
      qa[rt][ks] = *(const bf16x8*)(qbase + rt*2048 + ks*512 + fragoff);

  floatx4 O[2][8];
  #pragma unroll
  for (int rt = 0; rt < 2; rt++)
    #pragma unroll
    for (int ct = 0; ct < 8; ct++) O[rt][ct] = (floatx4){0.f,0.f,0.f,0.f};
  float lsum[2] = {0.f, 0.f};   // in-lane: row rt*16+c, this lane's k-col subset

  const unsigned short* kt0 = km + (size_t)b*NN*CC + (size_t)kh*(NN/KSPLIT)*CC;
  const unsigned short* vt0 = vm + (size_t)b*NN*CC + (size_t)kh*(NN/KSPLIT)*CC;

  const int ITERS = NN/KSPLIT/64;   // 8

  stage_tile(kt0, Kbuf[0], w, lane);
  __syncthreads();

  for (int it = 0; it < ITERS; it++) {
    const unsigned short* Kb = Kbuf[it & 1];
    // ---- V fragments for THIS iter: global -> regs (L1-shared across waves).
    // Issued first so their vmcnt doesn't force draining the K staging below.
    bf16x8 vreg[2][8];
    #pragma unroll
    for (int ks2 = 0; ks2 < 2; ks2++)
      #pragma unroll
      for (int ct = 0; ct < 8; ct++)
        vreg[ks2][ct] = *(const bf16x8*)(vt0 + (size_t)it*8192 + ks2*4096 + ct*512 + fragoff);
    // ---- prefetch next K tile into the other buffer (drained at iter-end barrier)
    if (it+1 < ITERS) stage_tile(kt0 + (size_t)(it+1)*8192, Kbuf[(it+1) & 1], w, lane);
    // ---- S^T = K Q^T from LDS: lane (c,quad) reg r = S[q_row=rt*16+c][ct*16+quad*4+r]
    floatx4 ST[2][4];
    #pragma unroll
    for (int rt = 0; rt < 2; rt++)
      #pragma unroll
      for (int ct = 0; ct < 4; ct++) ST[rt][ct] = (floatx4){0.f,0.f,0.f,0.f};
    #pragma unroll
    for (int ks = 0; ks < 4; ks++) {
      #pragma unroll
      for (int ct = 0; ct < 4; ct++) {
        bf16x8 kf = *(const bf16x8*)&Kb[ct*2048 + ks*512 + kvoff];
        ST[0][ct] = __builtin_amdgcn_mfma_f32_16x16x32_bf16(kf, qa[0][ks], ST[0][ct], 0, 0, 0);
        ST[1][ct] = __builtin_amdgcn_mfma_f32_16x16x32_bf16(kf, qa[1][ks], ST[1][ct], 0, 0, 0);
      }
    }
    // ---- P = exp2(S^T) (log2e folded into q); in-lane lsum; pack -> b64 writes ----
    #pragma unroll
    for (int rt = 0; rt < 2; rt++) {
      #pragma unroll
      for (int ct = 0; ct < 4; ct++) {
        float e0 = exp2f(ST[rt][ct][0]);
        float e1 = exp2f(ST[rt][ct][1]);
        float e2 = exp2f(ST[rt][ct][2]);
        float e3 = exp2f(ST[rt][ct][3]);
        lsum[rt] += (e0 + e1) + (e2 + e3);
        unsigned p01 = (__float_as_uint(e1) & 0xffff0000u) | (__float_as_uint(e0) >> 16);
        unsigned p23 = (__float_as_uint(e3) & 0xffff0000u) | (__float_as_uint(e2) >> 16);
        *(uint2*)&Pl[w][rt*16 + c][ct*16 + quad*4] = make_uint2(p01, p23);
      }
    }
    // ---- O += P V (P from wave-private LDS, V from regs) ----
    #pragma unroll
    for (int ks2 = 0; ks2 < 2; ks2++) {
      bf16x8 pa0 = *(const bf16x8*)(&Pl[w][c     ][ks2*32 + quad*8]);
      bf16x8 pa1 = *(const bf16x8*)(&Pl[w][16 + c][ks2*32 + quad*8]);
      #pragma unroll
      for (int ct = 0; ct < 8; ct++) {
        O[0][ct] = __builtin_amdgcn_mfma_f32_16x16x32_bf16(pa0, vreg[ks2][ct], O[0][ct], 0, 0, 0);
        O[1][ct] = __builtin_amdgcn_mfma_f32_16x16x32_bf16(pa1, vreg[ks2][ct], O[1][ct], 0, 0, 0);
      }
    }
    __syncthreads();   // all waves done with Kb; K(it+1) staging drained (vmcnt 0)
  }

  // ---- epilogue: wave-private; lsum butterfly over quads; packed O stores ----
  size_t nbase = (size_t)(kh*BB + b)*NN + blockIdx.x*128 + w*32;
  #pragma unroll
  for (int rt = 0; rt < 2; rt++) {
    float vsum = lsum[rt];
    vsum += __shfl_xor(vsum, 16);
    vsum += __shfl_xor(vsum, 32);
    if (lane < 16) lpart[nbase + rt*16 + lane] = vsum;
  }
  bool odd = (c & 1);
  int colpair = (c & ~1);
  #pragma unroll
  for (int rt = 0; rt < 2; rt++) {
    #pragma unroll
    for (int ct = 0; ct < 8; ct++) {
      unsigned u0 = f2bf(O[rt][ct][0]);
      unsigned u1 = f2bf(O[rt][ct][1]);
      unsigned u2 = f2bf(O[rt][ct][2]);
      unsigned u3 = f2bf(O[rt][ct][3]);
      // lane-pair exchange: even lane ends with rows {0,2}'s col pair, odd rows {1,3}
      unsigned s01 = odd ? u0 : u1;
      unsigned g01 = __shfl_xor((int)s01, 1);
      unsigned p0 = odd ? (g01 | (u1 << 16)) : (u0 | (g01 << 16));
      unsigned s23 = odd ? u2 : u3;
      unsigned g23 = __shfl_xor((int)s23, 1);
      unsigned p1 = odd ? (g23 | (u3 << 16)) : (u2 | (g23 << 16));
      int rowA = rt*16 + quad*4 + (odd ? 1 : 0);
      int rowB = rt*16 + quad*4 + (odd ? 3 : 2);
      *(unsigned*)(Opart + (nbase + rowA)*CC + ct*16 + colpair) = p0;
      *(unsigned*)(Opart + (nbase + rowB)*CC + ct*16 + colpair) = p1;
    }
  }
}

// ---- combine 8 partials + normalize + proj (MFMA) + bias + residual -> out [B,C,N]
//      16-row tiles: grid (NN/16, BB) = 512 blocks, 2/CU ----
__global__ __launch_bounds__(256, 2) void combine_kernel(
    const unsigned short* __restrict__ Opart, const float* __restrict__ lpart,
    const unsigned short* __restrict__ wpb, const float* __restrict__ bp,
    const float* __restrict__ x, float* __restrict__ out) {
  int b = blockIdx.y, n0 = blockIdx.x * 16;
  int t = threadIdx.x;
  __shared__ unsigned short hs[16][130];   // normalized attn output, bf16
  __shared__ float ps[16][132];            // proj result staging
  __shared__ float linv[16];
  if (t < 16) {
    float l = 0.f;
    #pragma unroll
    for (int kh = 0; kh < KSPLIT; kh++)
      l += lpart[((size_t)(kh*BB + b))*NN + n0 + t];
    linv[t] = 1.f / l;
  }
  __syncthreads();
  {
    int n = t >> 4, ch0 = (t & 15) * 8;   // 16 n x 16 chunks of 8 ch
    float acc[8];
    #pragma unroll
    for (int j = 0; j < 8; j++) acc[j] = 0.f;
    #pragma unroll
    for (int kh = 0; kh < KSPLIT; kh++) {
      uint4 a = *(const uint4*)(Opart + ((size_t)(kh*BB + b)*NN + n0 + n)*CC + ch0);
      unsigned uu[4] = {a.x, a.y, a.z, a.w};
      #pragma unroll
      for (int j = 0; j < 4; j++) {
        acc[j*2    ] += bf2f((unsigned short)(uu[j] & 0xffff));
        acc[j*2 + 1] += bf2f((unsigned short)(uu[j] >> 16));
      }
    }
    float li = linv[n];
    #pragma unroll
    for (int j = 0; j < 8; j++) hs[n][ch0 + j] = f2bf(acc[j] * li);
  }
  __syncthreads();
  int w = t >> 6, lane = t & 63, quad = lane >> 4, c = lane & 15;
  int o0 = w * 32;
  floatx4 acc[2];
  #pragma unroll
  for (int ct = 0; ct < 2; ct++) acc[ct] = (floatx4){0.f,0.f,0.f,0.f};
  #pragma unroll
  for (int ks = 0; ks < 4; ks++) {
    bf16x8 af = *(const bf16x8*)&hs[c][ks*32 + quad*8];
    #pragma unroll
    for (int ct = 0; ct < 2; ct++) {
      bf16x8 bfr = *(const bf16x8*)(wpb + (size_t)(o0 + ct*16 + c)*CC + ks*32 + quad*8);
      acc[ct] = __builtin_amdgcn_mfma_f32_16x16x32_bf16(af, bfr, acc[ct], 0, 0, 0);
    }
  }
  #pragma unroll
  for (int ct = 0; ct < 2; ct++)
    #pragma unroll
    for (int r = 0; r < 4; r++)
      ps[quad*4 + r][o0 + ct*16 + c] = acc[ct][r];
  __syncthreads();
  int o = t >> 1, nh = (t & 1) * 8;
  float bi = bp[o];
  const float* xr = x + ((size_t)b*CC + o)*NN + n0 + nh;
  float* orow = out + ((size_t)b*CC + o)*NN + n0 + nh;
  #pragma unroll
  for (int j4 = 0; j4 < 2; j4++) {
    float4 xv = ((const float4*)xr)[j4];
    float4 ov;
    ov.x = xv.x + ps[nh + j4*4 + 0][o] + bi;
    ov.y = xv.y + ps[nh + j4*4 + 1][o] + bi;
    ov.z = xv.z + ps[nh + j4*4 + 2][o] + bi;
    ov.w = xv.w + ps[nh + j4*4 + 3][o] + bi;
    ((float4*)orow)[j4] = ov;
  }
}

extern "C" void kernel_launch(void* const* d_in, const int* in_sizes, int n_in,
                              void* d_out, int out_size, void* d_ws, size_t ws_size,
                              hipStream_t stream) {
  const float* x    = (const float*)d_in[0];
  const float* gn_w = (const float*)d_in[1];
  const float* gn_b = (const float*)d_in[2];
  const float* wq   = (const float*)d_in[3];
  const float* bq   = (const float*)d_in[4];
  const float* wk   = (const float*)d_in[5];
  const float* bk   = (const float*)d_in[6];
  const float* wv   = (const float*)d_in[7];
  const float* bv   = (const float*)d_in[8];
  const float* wp   = (const float*)d_in[9];
  const float* bp   = (const float*)d_in[10];
  float* out = (float*)d_out;

  char* ws = (char*)d_ws;
  float2*         stats = (float2*)(ws);                       // 2048 B
  unsigned short* wqb   = (unsigned short*)(ws + 8192);        // 32 KiB each
  unsigned short* wkb   = (unsigned short*)(ws + 8192 + 32768);
  unsigned short* wvb   = (unsigned short*)(ws + 8192 + 65536);
  unsigned short* wpb   = (unsigned short*)(ws + 8192 + 98304);
  unsigned short* qb    = (unsigned short*)(ws + 262144);                  // 2 MiB
  unsigned short* kb    = (unsigned short*)(ws + 262144 + 2097152);        // 2 MiB
  unsigned short* vb    = (unsigned short*)(ws + 262144 + 2*2097152);      // 2 MiB
  unsigned short* Opart = (unsigned short*)(ws + 6553600);                 // 16 MiB
  float*          lpart = (float*)(ws + 6553600 + 16777216);               // 256 KiB

  gn_stats_kernel<<<dim3(320), 256, 0, stream>>>(x, stats, wq, wk, wv, wp,
                                                 wqb, wkb, wvb, wpb);
  qkv_kernel     <<<dim3(NN/16, BB), 256, 0, stream>>>(x, stats, gn_w, gn_b,
                                                       wqb, wkb, wvb, bq, bk, bv,
                                                       qb, kb, vb);
  attn_kernel    <<<dim3(NN/128, KSPLIT, BB), 256, 0, stream>>>(qb, kb, vb, Opart, lpart);
  combine_kernel <<<dim3(NN/16, BB), 256, 0, stream>>>(Opart, lpart, wpb, bp, x, out);
}

// Round 8
// 119.439 us; speedup vs baseline: 3.8874x; 1.0548x over previous
//
#include <hip/hip_runtime.h>
#include <math.h>

#define CC 128
#define NN 4096   // 16*16*16
#define BB 2
#define NGROUPS 32
#define CPG 4
#define GSIZE (CPG*NN)          // 16384 elements per (b, group)
#define KSPLIT 8

typedef __attribute__((ext_vector_type(8))) __bf16 bf16x8;
typedef __attribute__((ext_vector_type(4))) float floatx4;

__device__ __forceinline__ unsigned short f2bf(float f) {
  union { float f; unsigned u; } v; v.f = f;
  unsigned r = v.u + 0x7fff + ((v.u >> 16) & 1);   // RNE
  return (unsigned short)(r >> 16);
}
__device__ __forceinline__ float bf2f(unsigned short u) {
  return __uint_as_float(((unsigned)u) << 16);
}

// Tiled layouts (per batch, NN*CC elements):
//  Q/K: elem(n,ch) at (n>>4)*2048 + (ch>>5)*512 + (n&15)*32 + (ch&31)
//  V:   elem(ch,m) at (m>>5)*4096 + (ch>>4)*512 + (ch&15)*32 + (m&31)
//
// History: r6 diag: attn=24.3us of ~33us controllable (83us = harness fills).
// r7: V global->regs regressed (+9.5us) -> V stays in LDS. r8 (this): 8-wave
// 512-thread blocks, 1 block/CU, K AND V double-buffered (108KB LDS), ONE
// barrier/iter, staging overlaps the whole iter body. exp2-fold kept
// (q-scale includes log2e: exp(S) == exp2(S*log2e)).

// stage one 16KB tile with 8 waves: each wave 2 chunks of 1KB (lane-linear,
// 16B/lane). XOR-swizzle (r0): source slot q -> q ^ ((row>>1)&3) per
// 16-row x 32-short chunk; reads apply the same XOR (kvoff) -> identity.
__device__ __forceinline__ void stage_tile8(const unsigned short* __restrict__ gtile,
                                            unsigned short* ltile, int w, int lane) {
  int swl = ((lane >> 2) << 5) | ((((lane & 3) ^ ((lane >> 3) & 3))) << 3);
  #pragma unroll
  for (int j = 0; j < 2; j++) {
    int off = (w*2 + j) * 512;   // shorts; w in [0,8)
    __builtin_amdgcn_global_load_lds(
        (const __attribute__((address_space(1))) unsigned int*)(gtile + off + swl),
        (__attribute__((address_space(3))) unsigned int*)(ltile + off),
        16, 0, 0);
  }
}

// ---- stage 1 (320 blocks): 0-255 GN partial sums; 256-319 weight f32->bf16 ----
__global__ void gn_stats_kernel(const float* __restrict__ x, float2* __restrict__ stats,
                                const float* __restrict__ wq, const float* __restrict__ wk,
                                const float* __restrict__ wv, const float* __restrict__ wp,
                                unsigned short* __restrict__ wqb, unsigned short* __restrict__ wkb,
                                unsigned short* __restrict__ wvb, unsigned short* __restrict__ wpb) {
  int t = threadIdx.x;
  if (blockIdx.x < 256) {
    int bid = blockIdx.x;
    const float4* base = (const float4*)(x + (size_t)bid * 4096);
    float4 v = base[t];
    float s  = v.x + v.y + v.z + v.w;
    float ss = v.x*v.x + v.y*v.y + v.z*v.z + v.w*v.w;
    #pragma unroll
    for (int off = 1; off < 64; off <<= 1) {
      s  += __shfl_xor(s, off);
      ss += __shfl_xor(ss, off);
    }
    __shared__ float sred[4], ssred[4];
    if ((t & 63) == 0) { sred[t >> 6] = s; ssred[t >> 6] = ss; }
    __syncthreads();
    if (t == 0)
      stats[bid] = make_float2(sred[0]+sred[1]+sred[2]+sred[3],
                               ssred[0]+ssred[1]+ssred[2]+ssred[3]);
  } else {
    const float sc = 0.1275174389522736f;    // 128^-0.5 * log2(e), folded into wq
    int i = (blockIdx.x - 256) * 256 + t;    // float4 index; 4096 per weight
    int id = i >> 12, local = i & 4095;
    const float* src = id==0 ? wq : id==1 ? wk : id==2 ? wv : wp;
    unsigned short* dst = id==0 ? wqb : id==1 ? wkb : id==2 ? wvb : wpb;
    float s = (id == 0) ? sc : 1.0f;
    float4 v = ((const float4*)src)[local];
    unsigned p0 = (unsigned)f2bf(v.x*s) | ((unsigned)f2bf(v.y*s) << 16);
    unsigned p1 = (unsigned)f2bf(v.z*s) | ((unsigned)f2bf(v.w*s) << 16);
    ((uint2*)dst)[local] = make_uint2(p0, p1);
  }
}

// ---- fused q/k/v: one 16-row tile per block computes all three convs (A-frags
// loaded once, reused 3x). grid (NN/16, BB) = 512 blocks, 2/CU. ----
__global__ __launch_bounds__(256, 2) void qkv_kernel(
    const float* __restrict__ x, const float2* __restrict__ stats,
    const float* __restrict__ gamma, const float* __restrict__ beta,
    const unsigned short* __restrict__ wqb, const unsigned short* __restrict__ wkb,
    const unsigned short* __restrict__ wvb,
    const float* __restrict__ bq, const float* __restrict__ bk, const float* __restrict__ bv,
    unsigned short* __restrict__ q, unsigned short* __restrict__ k, unsigned short* __restrict__ v) {
  int b = blockIdx.y, n0 = blockIdx.x * 16;
  __shared__ unsigned short hs[16][130];   // normalized x tile, bf16 [n][c]
  __shared__ unsigned short vs[16][136];   // v transpose staging
  __shared__ float gm[NGROUPS], gr[NGROUPS], aa[CC], ab[CC];
  int t = threadIdx.x;
  if (t < NGROUPS) {
    float su = 0.f, ssq = 0.f;
    #pragma unroll
    for (int j = 0; j < 4; j++) {
      float2 p = stats[(b*NGROUPS + t)*4 + j];
      su += p.x; ssq += p.y;
    }
    float mean = su * (1.0f/GSIZE);
    float var  = ssq * (1.0f/GSIZE) - mean*mean;
    gm[t] = mean;
    gr[t] = rsqrtf(var + 1e-5f);
  }
  __syncthreads();
  if (t < CC) {
    int g = t >> 2;
    float a = gr[g] * gamma[t];
    aa[t] = a;
    ab[t] = beta[t] - gm[g] * a;
  }
  __syncthreads();
  // x tile: 16 rows x 128 ch = 512 float4 over 256 threads
  #pragma unroll
  for (int j = 0; j < 2; j++) {
    int idx = j*256 + t;
    int c = idx >> 2, n4 = idx & 3;
    float4 xv = *(const float4*)(x + ((size_t)b*CC + c)*NN + n0 + n4*4);
    float a = aa[c], bc = ab[c];
    hs[n4*4+0][c] = f2bf(a*xv.x + bc);
    hs[n4*4+1][c] = f2bf(a*xv.y + bc);
    hs[n4*4+2][c] = f2bf(a*xv.z + bc);
    hs[n4*4+3][c] = f2bf(a*xv.w + bc);
  }
  __syncthreads();
  int w = t >> 6, lane = t & 63, quad = lane >> 4, c = lane & 15;
  int o0 = w * 32;
  // A-fragments once, reused for q/k/v
  bf16x8 af[4];
  #pragma unroll
  for (int ks = 0; ks < 4; ks++)
    af[ks] = *(const bf16x8*)&hs[c][ks*32 + quad*8];
  floatx4 aq[2], ak[2], av[2];
  #pragma unroll
  for (int ct = 0; ct < 2; ct++) {
    aq[ct] = (floatx4){0.f,0.f,0.f,0.f};
    ak[ct] = (floatx4){0.f,0.f,0.f,0.f};
    av[ct] = (floatx4){0.f,0.f,0.f,0.f};
  }
  #pragma unroll
  for (int ks = 0; ks < 4; ks++) {
    #pragma unroll
    for (int ct = 0; ct < 2; ct++) {
      size_t woff = (size_t)(o0 + ct*16 + c)*CC + ks*32 + quad*8;
      bf16x8 bq8 = *(const bf16x8*)(wqb + woff);
      bf16x8 bk8 = *(const bf16x8*)(wkb + woff);
      bf16x8 bv8 = *(const bf16x8*)(wvb + woff);
      aq[ct] = __builtin_amdgcn_mfma_f32_16x16x32_bf16(af[ks], bq8, aq[ct], 0, 0, 0);
      ak[ct] = __builtin_amdgcn_mfma_f32_16x16x32_bf16(af[ks], bk8, ak[ct], 0, 0, 0);
      av[ct] = __builtin_amdgcn_mfma_f32_16x16x32_bf16(af[ks], bv8, av[ct], 0, 0, 0);
    }
  }
  // q,k tiled stores: this block covers exactly n-tile blockIdx.x
  {
    const float sc = 0.1275174389522736f;   // matches wq fold (incl. log2e)
    size_t base = (size_t)b*NN*CC + (size_t)blockIdx.x*2048 + w*512;
    #pragma unroll
    for (int ct = 0; ct < 2; ct++) {
      float bqi = bq[o0 + ct*16 + c] * sc;
      float bki = bk[o0 + ct*16 + c];
      #pragma unroll
      for (int r = 0; r < 4; r++) {
        int idx = (quad*4 + r)*32 + ct*16 + c;
        q[base + idx] = f2bf(aq[ct][r] + bqi);
        k[base + idx] = f2bf(ak[ct][r] + bki);
      }
    }
  }
  // v transpose via LDS then tiled V store
  #pragma unroll
  for (int ct = 0; ct < 2; ct++) {
    float bvi = bv[o0 + ct*16 + c];
    #pragma unroll
    for (int r = 0; r < 4; r++)
      vs[quad*4 + r][o0 + ct*16 + c] = f2bf(av[ct][r] + bvi);
  }
  __syncthreads();
  {
    // elem(ch,m): (m>>5)*4096 + (ch>>4)*512 + (ch&15)*32 + (m&31); our m = n0..n0+15
    int ch = t >> 1, part = t & 1;      // 8 m per thread
    int mbase = (n0 & 16) + part*8;
    unsigned pk[4];
    #pragma unroll
    for (int j = 0; j < 4; j++) {
      unsigned lo = vs[part*8 + j*2    ][ch];
      unsigned hi = vs[part*8 + j*2 + 1][ch];
      pk[j] = lo | (hi << 16);
    }
    *(uint4*)(v + (size_t)b*NN*CC + ((size_t)(n0 >> 5))*4096 + (ch >> 4)*512
              + (ch & 15)*32 + mbase) = make_uint4(pk[0], pk[1], pk[2], pk[3]);
  }
}

// ---- MFMA flash attention, r8: 256 q-rows/block (8 waves x 32), 512 thr,
// grid (NN/256, KSPLIT, BB) = (16,8,2) = 256 blocks = 1/CU exactly.
// K AND V double-buffered in LDS (108 KB total): ONE barrier per iter; both
// next-tile stagings issued at iter top, overlapped by QK+softmax+PV, drained
// at the iter-end barrier. Pl wave-private (in-order DS ops, no barrier).
// 2 waves/SIMD occupancy (same as r6); staging writes halved vs r6. ----
__global__ __launch_bounds__(512, 2) void attn_kernel(
    const unsigned short* __restrict__ qm,  // tiled QK layout, q-scale (incl log2e) folded
    const unsigned short* __restrict__ km,  // tiled QK layout
    const unsigned short* __restrict__ vm,  // tiled V layout
    unsigned short* __restrict__ Opart,     // [KSPLIT][B][N][C] bf16, unnormalized
    float* __restrict__ lpart) {            // [KSPLIT][B][N] f32
  int b    = blockIdx.z;
  int kh   = blockIdx.y;
  int t    = threadIdx.x;
  int w    = t >> 6, lane = t & 63, quad = lane >> 4, c = lane & 15;

  __shared__ unsigned short Kbuf[2][8192];   // 2 x 16 KB
  __shared__ unsigned short Vbuf[2][8192];   // 2 x 16 KB
  __shared__ unsigned short Pl[8][32][88];   // wave-private P, 45 KB

  int fragoff = c*32 + quad*8;                               // natural frag offset
  int kvoff   = (c << 5) | (((quad ^ ((c >> 1) & 3))) << 3); // swizzled LDS frag

  bf16x8 qa[2][4];
  const unsigned short* qbase = qm + (size_t)b*NN*CC + ((size_t)(blockIdx.x*16 + w*2))*2048;
  #pragma unroll
  for (int rt = 0; rt < 2; rt++)
    #pragma unroll
    for (int ks = 0; ks < 4; ks++)
      qa[rt][ks] = *(const bf16x8*)(qbase + rt*2048 + ks*512 + fragoff);

  floatx4 O[2][8];
  #pragma unroll
  for (int rt = 0; rt < 2; rt++)
    #pragma unroll
    for (int ct = 0; ct < 8; ct++) O[rt][ct] = (floatx4){0.f,0.f,0.f,0.f};
  float lsum[2] = {0.f, 0.f};   // in-lane: row rt*16+c, this lane's k-col subset

  const unsigned short* kt0 = km + (size_t)b*NN*CC + (size_t)kh*(NN/KSPLIT)*CC;
  const unsigned short* vt0 = vm + (size_t)b*NN*CC + (size_t)kh*(NN/KSPLIT)*CC;

  const int ITERS = NN/KSPLIT/64;   // 8

  stage_tile8(kt0, Kbuf[0], w, lane);
  stage_tile8(vt0, Vbuf[0], w, lane);
  __syncthreads();

  for (int it = 0; it < ITERS; it++) {
    const unsigned short* Kb = Kbuf[it & 1];
    const unsigned short* Vb = Vbuf[it & 1];
    // ---- prefetch next K and V tiles into the other buffers; their vmcnt is
    // drained by the compiler-emitted wait at the iter-end barrier, so the
    // full QK+softmax+PV body covers the latency. Safe: buf[(it+1)&1] was
    // last read in iter it-1, before the barrier we just crossed. ----
    if (it+1 < ITERS) {
      stage_tile8(kt0 + (size_t)(it+1)*8192, Kbuf[(it+1) & 1], w, lane);
      stage_tile8(vt0 + (size_t)(it+1)*8192, Vbuf[(it+1) & 1], w, lane);
    }
    // ---- S^T = K Q^T from LDS: lane (c,quad) reg r = S[q_row=rt*16+c][ct*16+quad*4+r]
    floatx4 ST[2][4];
    #pragma unroll
    for (int rt = 0; rt < 2; rt++)
      #pragma unroll
      for (int ct = 0; ct < 4; ct++) ST[rt][ct] = (floatx4){0.f,0.f,0.f,0.f};
    #pragma unroll
    for (int ks = 0; ks < 4; ks++) {
      #pragma unroll
      for (int ct = 0; ct < 4; ct++) {
        bf16x8 kf = *(const bf16x8*)&Kb[ct*2048 + ks*512 + kvoff];
        ST[0][ct] = __builtin_amdgcn_mfma_f32_16x16x32_bf16(kf, qa[0][ks], ST[0][ct], 0, 0, 0);
        ST[1][ct] = __builtin_amdgcn_mfma_f32_16x16x32_bf16(kf, qa[1][ks], ST[1][ct], 0, 0, 0);
      }
    }
    // ---- P = exp2(S^T) (log2e folded into q); in-lane lsum; pack -> b64 writes ----
    #pragma unroll
    for (int rt = 0; rt < 2; rt++) {
      #pragma unroll
      for (int ct = 0; ct < 4; ct++) {
        float e0 = exp2f(ST[rt][ct][0]);
        float e1 = exp2f(ST[rt][ct][1]);
        float e2 = exp2f(ST[rt][ct][2]);
        float e3 = exp2f(ST[rt][ct][3]);
        lsum[rt] += (e0 + e1) + (e2 + e3);
        unsigned p01 = (__float_as_uint(e1) & 0xffff0000u) | (__float_as_uint(e0) >> 16);
        unsigned p23 = (__float_as_uint(e3) & 0xffff0000u) | (__float_as_uint(e2) >> 16);
        *(uint2*)&Pl[w][rt*16 + c][ct*16 + quad*4] = make_uint2(p01, p23);
      }
    }
    // ---- O += P V (P wave-private LDS, V from LDS) ----
    #pragma unroll
    for (int ks2 = 0; ks2 < 2; ks2++) {
      bf16x8 pa0 = *(const bf16x8*)(&Pl[w][c     ][ks2*32 + quad*8]);
      bf16x8 pa1 = *(const bf16x8*)(&Pl[w][16 + c][ks2*32 + quad*8]);
      #pragma unroll
      for (int ct = 0; ct < 8; ct++) {
        bf16x8 vf = *(const bf16x8*)&Vb[ks2*4096 + ct*512 + kvoff];
        O[0][ct] = __builtin_amdgcn_mfma_f32_16x16x32_bf16(pa0, vf, O[0][ct], 0, 0, 0);
        O[1][ct] = __builtin_amdgcn_mfma_f32_16x16x32_bf16(pa1, vf, O[1][ct], 0, 0, 0);
      }
    }
    __syncthreads();   // waves done with Kb/Vb; next-tile staging drained
  }

  // ---- epilogue: wave-private; lsum butterfly over quads; packed O stores ----
  size_t nbase = (size_t)(kh*BB + b)*NN + blockIdx.x*256 + w*32;
  #pragma unroll
  for (int rt = 0; rt < 2; rt++) {
    float vsum = lsum[rt];
    vsum += __shfl_xor(vsum, 16);
    vsum += __shfl_xor(vsum, 32);
    if (lane < 16) lpart[nbase + rt*16 + lane] = vsum;
  }
  bool odd = (c & 1);
  int colpair = (c & ~1);
  #pragma unroll
  for (int rt = 0; rt < 2; rt++) {
    #pragma unroll
    for (int ct = 0; ct < 8; ct++) {
      unsigned u0 = f2bf(O[rt][ct][0]);
      unsigned u1 = f2bf(O[rt][ct][1]);
      unsigned u2 = f2bf(O[rt][ct][2]);
      unsigned u3 = f2bf(O[rt][ct][3]);
      // lane-pair exchange: even lane ends with rows {0,2}'s col pair, odd rows {1,3}
      unsigned s01 = odd ? u0 : u1;
      unsigned g01 = __shfl_xor((int)s01, 1);
      unsigned p0 = odd ? (g01 | (u1 << 16)) : (u0 | (g01 << 16));
      unsigned s23 = odd ? u2 : u3;
      unsigned g23 = __shfl_xor((int)s23, 1);
      unsigned p1 = odd ? (g23 | (u3 << 16)) : (u2 | (g23 << 16));
      int rowA = rt*16 + quad*4 + (odd ? 1 : 0);
      int rowB = rt*16 + quad*4 + (odd ? 3 : 2);
      *(unsigned*)(Opart + (nbase + rowA)*CC + ct*16 + colpair) = p0;
      *(unsigned*)(Opart + (nbase + rowB)*CC + ct*16 + colpair) = p1;
    }
  }
}

// ---- combine 8 partials + normalize + proj (MFMA) + bias + residual -> out [B,C,N]
//      16-row tiles: grid (NN/16, BB) = 512 blocks, 2/CU ----
__global__ __launch_bounds__(256, 2) void combine_kernel(
    const unsigned short* __restrict__ Opart, const float* __restrict__ lpart,
    const unsigned short* __restrict__ wpb, const float* __restrict__ bp,
    const float* __restrict__ x, float* __restrict__ out) {
  int b = blockIdx.y, n0 = blockIdx.x * 16;
  int t = threadIdx.x;
  __shared__ unsigned short hs[16][130];   // normalized attn output, bf16
  __shared__ float ps[16][132];            // proj result staging
  __shared__ float linv[16];
  if (t < 16) {
    float l = 0.f;
    #pragma unroll
    for (int kh = 0; kh < KSPLIT; kh++)
      l += lpart[((size_t)(kh*BB + b))*NN + n0 + t];
    linv[t] = 1.f / l;
  }
  __syncthreads();
  {
    int n = t >> 4, ch0 = (t & 15) * 8;   // 16 n x 16 chunks of 8 ch
    float acc[8];
    #pragma unroll
    for (int j = 0; j < 8; j++) acc[j] = 0.f;
    #pragma unroll
    for (int kh = 0; kh < KSPLIT; kh++) {
      uint4 a = *(const uint4*)(Opart + ((size_t)(kh*BB + b)*NN + n0 + n)*CC + ch0);
      unsigned uu[4] = {a.x, a.y, a.z, a.w};
      #pragma unroll
      for (int j = 0; j < 4; j++) {
        acc[j*2    ] += bf2f((unsigned short)(uu[j] & 0xffff));
        acc[j*2 + 1] += bf2f((unsigned short)(uu[j] >> 16));
      }
    }
    float li = linv[n];
    #pragma unroll
    for (int j = 0; j < 8; j++) hs[n][ch0 + j] = f2bf(acc[j] * li);
  }
  __syncthreads();
  int w = t >> 6, lane = t & 63, quad = lane >> 4, c = lane & 15;
  int o0 = w * 32;
  floatx4 acc[2];
  #pragma unroll
  for (int ct = 0; ct < 2; ct++) acc[ct] = (floatx4){0.f,0.f,0.f,0.f};
  #pragma unroll
  for (int ks = 0; ks < 4; ks++) {
    bf16x8 af = *(const bf16x8*)&hs[c][ks*32 + quad*8];
    #pragma unroll
    for (int ct = 0; ct < 2; ct++) {
      bf16x8 bfr = *(const bf16x8*)(wpb + (size_t)(o0 + ct*16 + c)*CC + ks*32 + quad*8);
      acc[ct] = __builtin_amdgcn_mfma_f32_16x16x32_bf16(af, bfr, acc[ct], 0, 0, 0);
    }
  }
  #pragma unroll
  for (int ct = 0; ct < 2; ct++)
    #pragma unroll
    for (int r = 0; r < 4; r++)
      ps[quad*4 + r][o0 + ct*16 + c] = acc[ct][r];
  __syncthreads();
  int o = t >> 1, nh = (t & 1) * 8;
  float bi = bp[o];
  const float* xr = x + ((size_t)b*CC + o)*NN + n0 + nh;
  float* orow = out + ((size_t)b*CC + o)*NN + n0 + nh;
  #pragma unroll
  for (int j4 = 0; j4 < 2; j4++) {
    float4 xv = ((const float4*)xr)[j4];
    float4 ov;
    ov.x = xv.x + ps[nh + j4*4 + 0][o] + bi;
    ov.y = xv.y + ps[nh + j4*4 + 1][o] + bi;
    ov.z = xv.z + ps[nh + j4*4 + 2][o] + bi;
    ov.w = xv.w + ps[nh + j4*4 + 3][o] + bi;
    ((float4*)orow)[j4] = ov;
  }
}

extern "C" void kernel_launch(void* const* d_in, const int* in_sizes, int n_in,
                              void* d_out, int out_size, void* d_ws, size_t ws_size,
                              hipStream_t stream) {
  const float* x    = (const float*)d_in[0];
  const float* gn_w = (const float*)d_in[1];
  const float* gn_b = (const float*)d_in[2];
  const float* wq   = (const float*)d_in[3];
  const float* bq   = (const float*)d_in[4];
  const float* wk   = (const float*)d_in[5];
  const float* bk   = (const float*)d_in[6];
  const float* wv   = (const float*)d_in[7];
  const float* bv   = (const float*)d_in[8];
  const float* wp   = (const float*)d_in[9];
  const float* bp   = (const float*)d_in[10];
  float* out = (float*)d_out;

  char* ws = (char*)d_ws;
  float2*         stats = (float2*)(ws);                       // 2048 B
  unsigned short* wqb   = (unsigned short*)(ws + 8192);        // 32 KiB each
  unsigned short* wkb   = (unsigned short*)(ws + 8192 + 32768);
  unsigned short* wvb   = (unsigned short*)(ws + 8192 + 65536);
  unsigned short* wpb   = (unsigned short*)(ws + 8192 + 98304);
  unsigned short* qb    = (unsigned short*)(ws + 262144);                  // 2 MiB
  unsigned short* kb    = (unsigned short*)(ws + 262144 + 2097152);        // 2 MiB
  unsigned short* vb    = (unsigned short*)(ws + 262144 + 2*2097152);      // 2 MiB
  unsigned short* Opart = (unsigned short*)(ws + 6553600);                 // 16 MiB
  float*          lpart = (float*)(ws + 6553600 + 16777216);               // 256 KiB

  gn_stats_kernel<<<dim3(320), 256, 0, stream>>>(x, stats, wq, wk, wv, wp,
                                                 wqb, wkb, wvb, wpb);
  qkv_kernel     <<<dim3(NN/16, BB), 256, 0, stream>>>(x, stats, gn_w, gn_b,
                                                       wqb, wkb, wvb, bq, bk, bv,
                                                       qb, kb, vb);
  attn_kernel    <<<dim3(NN/256, KSPLIT, BB), 512, 0, stream>>>(qb, kb, vb, Opart, lpart);
  combine_kernel <<<dim3(NN/16, BB), 256, 0, stream>>>(Opart, lpart, wpb, bp, x, out);
}